// Round 20
// baseline (632.830 us; speedup 1.0000x reference)
//
#include <hip/hip_runtime.h>
#include <stdint.h>

#define QD 2048
#define KD 1024
#define HID 1024
#define NH 16
#define HD 64
#define CMBD 3072   // QD + KD

typedef float  f32x4   __attribute__((ext_vector_type(4)));
typedef short  short8  __attribute__((ext_vector_type(8)));
typedef short  short4v __attribute__((ext_vector_type(4)));
typedef float  float4v __attribute__((ext_vector_type(4)));

__device__ inline float bf2f(short s) {
  unsigned u = ((unsigned)(unsigned short)s) << 16;
  return __builtin_bit_cast(float, u);
}
__device__ inline short f2bf(float f) {
  unsigned u = __builtin_bit_cast(unsigned, f);
  u = u + 0x7fff + ((u >> 16) & 1);
  return (short)(u >> 16);
}
// e4m3fn (OCP), RNE, saturating
__device__ inline unsigned char f2f8(float f) {
  unsigned u = __builtin_bit_cast(unsigned, f);
  unsigned s = (u >> 24) & 0x80u;
  float a = fabsf(f);
  if (a >= 448.f) return (unsigned char)(s | 0x7E);
  if (a < 0.015625f) {
    int m = (int)(a * 512.f + 0.5f);
    if (m > 7) return (unsigned char)(s | 0x08);
    return (unsigned char)(s | m);
  }
  int ebits = (int)((u >> 23) & 0xFF) - 127;
  unsigned mant = u & 0x7FFFFF;
  unsigned keep = mant >> 20;
  unsigned rest = mant & 0xFFFFF;
  keep += (rest > 0x80000u) || (rest == 0x80000u && (keep & 1));
  if (keep == 8) { keep = 0; ebits += 1; }
  if (ebits > 8) return (unsigned char)(s | 0x7E);
  return (unsigned char)(s | ((unsigned)(ebits + 7) << 3) | keep);
}

// fp8 frag-blocked layout: addr(r,k) = (r>>8)*786432 + (k>>5)*8192 +
//   ((r>>4)&15)*512 + ((k>>3)&3)*128 + (r&15)*8 + (k&7)
__device__ inline size_t fp8addr(int r, int k) {
  return (size_t)(r >> 8) * 786432 + (size_t)(k >> 5) * 8192 +
         (size_t)((r >> 4) & 15) * 512 + (size_t)((k >> 3) & 3) * 128 +
         (size_t)(r & 15) * 8;
}

// ---------------------------------------------------------------- conversions
// 8 f32/thread: bf16 natural layout + fp8 frag-blocked layout
__global__ void cvt_inputs(const float* __restrict__ qf, const float* __restrict__ kf,
                           short* __restrict__ cmb, unsigned char* __restrict__ cmb8,
                           int qblocks) {
  const int b = blockIdx.x, t = threadIdx.x;
  int r, k;
  const float* src;
  if (b < qblocks) { const int i = b * 256 + t; r = i >> 8; k = (i & 255) * 8; src = qf + (size_t)r * QD + k; }
  else             { const int i = (b - qblocks) * 256 + t; r = i >> 7; k = (i & 127) * 8; src = kf + (size_t)r * KD + k; k += QD; }
  float4v v0 = *(const float4v*)src;
  float4v v1 = *(const float4v*)(src + 4);
  short8 o;
  o[0] = f2bf(v0[0]); o[1] = f2bf(v0[1]); o[2] = f2bf(v0[2]); o[3] = f2bf(v0[3]);
  o[4] = f2bf(v1[0]); o[5] = f2bf(v1[1]); o[6] = f2bf(v1[2]); o[7] = f2bf(v1[3]);
  *(short8*)(cmb + (size_t)r * CMBD + k) = o;
  unsigned long long p =
      (unsigned long long)f2f8(v0[0])        | ((unsigned long long)f2f8(v0[1]) << 8)  |
      ((unsigned long long)f2f8(v0[2]) << 16)| ((unsigned long long)f2f8(v0[3]) << 24) |
      ((unsigned long long)f2f8(v1[0]) << 32)| ((unsigned long long)f2f8(v1[1]) << 40) |
      ((unsigned long long)f2f8(v1[2]) << 48)| ((unsigned long long)f2f8(v1[3]) << 56);
  *(unsigned long long*)(cmb8 + fp8addr(r, k)) = p;
}

struct WSeg { const float* s; short* d; int blkEnd; };
__global__ void cvt_weights(WSeg s0, WSeg s1, WSeg s2, WSeg s3) {
  int b = blockIdx.x;
  WSeg seg; int base;
  if      (b < s0.blkEnd) { seg = s0; base = 0; }
  else if (b < s1.blkEnd) { seg = s1; base = s0.blkEnd; }
  else if (b < s2.blkEnd) { seg = s2; base = s1.blkEnd; }
  else                    { seg = s3; base = s2.blkEnd; }
  const size_t i = ((size_t)(b - base) * 256 + threadIdx.x) * 4;
  float4v v = *(const float4v*)(seg.s + i);
  short4v o;
  o[0] = f2bf(v[0]); o[1] = f2bf(v[1]); o[2] = f2bf(v[2]); o[3] = f2bf(v[3]);
  *(short4v*)(seg.d + i) = o;
}

// Wg1||Wc1 -> fp8 frag-blocked wgc8; grid(96 kt, 8 band), 4 pieces/thread
__global__ void cvt_w8(const float* __restrict__ Wg1, const float* __restrict__ Wc1,
                       unsigned char* __restrict__ wgc8) {
  const int kt = blockIdx.x, band = blockIdx.y;
  unsigned char* dst = wgc8 + (size_t)band * 786432 + (size_t)kt * 8192;
  for (int p = threadIdx.x; p < 1024; p += 256) {
    const int grp = p >> 6, kq = (p >> 4) & 3, fr = p & 15;
    const int c = band * 256 + grp * 16 + fr;
    const int k = kt * 32 + kq * 8;
    const float* s = (c < 1024 ? Wg1 + (size_t)c * CMBD : Wc1 + (size_t)(c - 1024) * CMBD) + k;
    float4v v0 = *(const float4v*)s;
    float4v v1 = *(const float4v*)(s + 4);
    unsigned long long pk =
        (unsigned long long)f2f8(v0[0])        | ((unsigned long long)f2f8(v0[1]) << 8)  |
        ((unsigned long long)f2f8(v0[2]) << 16)| ((unsigned long long)f2f8(v0[3]) << 24) |
        ((unsigned long long)f2f8(v1[0]) << 32)| ((unsigned long long)f2f8(v1[1]) << 40) |
        ((unsigned long long)f2f8(v1[2]) << 48)| ((unsigned long long)f2f8(v1[3]) << 56);
    *(unsigned long long*)(dst + p * 8) = pk;
  }
}

// ---------------------------------------------------------------- pack
__global__ void pack_params(float* __restrict__ egp, int egpN,
                            const float* __restrict__ bg1, const float* __restrict__ bc1,
                            const float* __restrict__ bk,  const float* __restrict__ bvk,
                            const float* __restrict__ Wg2, const float* __restrict__ Wc2,
                            float* __restrict__ bgc, float* __restrict__ bkv,
                            float* __restrict__ w2gc) {
  int i = blockIdx.x * 256 + threadIdx.x;
  if (i < egpN) { egp[i] = 0.f; return; }
  i -= egpN;
  const int seg = i >> 10, idx = i & 1023;
  switch (seg) {
    case 0: bgc[idx]         = bg1[idx]; break;
    case 1: bgc[1024 + idx]  = bc1[idx]; break;
    case 2: bkv[idx]         = bk[idx];  break;
    case 3: bkv[1024 + idx]  = bvk[idx]; break;
    case 4: w2gc[idx]        = Wg2[idx]; break;
    case 5: w2gc[1024 + idx] = Wc2[idx]; break;
  }
}

// ---------------------------------------------------------------- common GEMM defs
#define EPI_NONE 0

typedef const __attribute__((address_space(1))) void gvoid_t;
typedef __attribute__((address_space(3))) void lvoid_t;

#define WAIT_VM(n)  asm volatile("s_waitcnt vmcnt(" #n ")" ::: "memory")

#define APAN(b, kp) (((b) * 2 + (kp)) * 8192)
#define BPAN(b, kp) (32768 + ((b) * 2 + (kp)) * 8192)

#define PHASE_MID                                        \
  __builtin_amdgcn_s_barrier();                          \
  asm volatile("s_waitcnt lgkmcnt(0)" ::: "memory");     \
  __builtin_amdgcn_s_setprio(1);

#define PHASE_END                                        \
  __builtin_amdgcn_s_setprio(0);                         \
  __builtin_amdgcn_s_barrier();

// ---------------------------------------------------------------- bf16 256x256 GEMM (verified) — Q/KV/O
template<int EPI>
__global__ __launch_bounds__(512, 2)
void gemm256(const short* __restrict__ A, size_t lda,
             const short* __restrict__ W,
             const float* __restrict__ bias,
             short* __restrict__ C, int N, int K,
             const float* __restrict__ w2, float* __restrict__ egp, int rowsTot) {
  extern __shared__ short ls[];
  const int tid  = threadIdx.x;
  const int lane = tid & 63;
  const int wave = tid >> 6;
  const int wm = wave >> 2, wn = wave & 3;
  const int fr = lane & 15, kq4 = lane >> 4;

  const int nwg = gridDim.x * gridDim.y;
  const int lin = blockIdx.y * gridDim.x + blockIdx.x;
  const int cpx = nwg >> 3;
  const int nid = (lin & 7) * cpx + (lin >> 3);
  const int bx = nid % gridDim.x, by = nid / gridDim.x;
  const size_t rowBase = (size_t)by * 256;
  const size_t colBase = (size_t)bx * 256;

  const int NTT = K >> 6;

  f32x4 acc[8][4];
#pragma unroll
  for (int mi = 0; mi < 8; mi++)
#pragma unroll
    for (int ni = 0; ni < 4; ni++) acc[mi][ni] = (f32x4){0.f, 0.f, 0.f, 0.f};

  const int frsw = (kq4 ^ ((fr >> 1) & 3)) * 8;

  const int grow  = tid >> 2;
  const int slotx = (tid & 3) ^ ((tid >> 3) & 3);
  const short* gAlo = A + (rowBase + grow) * lda + slotx * 8;
  const short* gAhi = gAlo + (size_t)128 * lda;
  const short* gBlo = W + (colBase + grow) * (size_t)K + slotx * 8;
  const short* gBhi = gBlo + (size_t)128 * K;
  short* const sdst = ls + tid * 8;

  auto STG_A = [&](int panOff, int kcol) {
    __builtin_amdgcn_global_load_lds((gvoid_t*)(gAlo + kcol), (lvoid_t*)(sdst + panOff),        16, 0, 0);
    __builtin_amdgcn_global_load_lds((gvoid_t*)(gAhi + kcol), (lvoid_t*)(sdst + panOff + 4096), 16, 0, 0);
  };
  auto STG_B = [&](int panOff, int kcol) {
    __builtin_amdgcn_global_load_lds((gvoid_t*)(gBlo + kcol), (lvoid_t*)(sdst + panOff),        16, 0, 0);
    __builtin_amdgcn_global_load_lds((gvoid_t*)(gBhi + kcol), (lvoid_t*)(sdst + panOff + 4096), 16, 0, 0);
  };

  STG_A(APAN(0, 0), 0);  STG_A(APAN(0, 1), 32);
  STG_B(BPAN(0, 0), 0);  STG_B(BPAN(0, 1), 32);
  STG_B(BPAN(1, 0), 64); STG_B(BPAN(1, 1), 96);
  WAIT_VM(4);
  __builtin_amdgcn_s_barrier();

  short8 fa0[8], fa1[8], fb0[4], fb1[4];

  for (int t = 0; t < NTT; t += 2) {
    const bool more = (t + 2 < NTT);
    const int kA1 = (t + 1) * 64;
    const int kE2 = (t + 2) * 64;
    const int kO3 = (t + 3) * 64;

#pragma unroll
    for (int m = 0; m < 4; m++) {
      const int r = (wm * 128 + m * 16 + fr) * 32 + frsw;
      fa0[m * 2 + 0] = *(const short8*)(ls + APAN(0, 0) + r);
      fa0[m * 2 + 1] = *(const short8*)(ls + APAN(0, 1) + r);
    }
#pragma unroll
    for (int n = 0; n < 2; n++) {
      const int r = (wn * 64 + n * 16 + fr) * 32 + frsw;
      fb0[n * 2 + 0] = *(const short8*)(ls + BPAN(0, 0) + r);
      fb0[n * 2 + 1] = *(const short8*)(ls + BPAN(0, 1) + r);
    }
    STG_A(APAN(1, 0), kA1);
    PHASE_MID
#pragma unroll
    for (int m = 0; m < 4; m++)
#pragma unroll
      for (int n = 0; n < 2; n++) {
        acc[m][n] = __builtin_amdgcn_mfma_f32_16x16x32_bf16(fa0[m*2+0], fb0[n*2+0], acc[m][n], 0, 0, 0);
        acc[m][n] = __builtin_amdgcn_mfma_f32_16x16x32_bf16(fa0[m*2+1], fb0[n*2+1], acc[m][n], 0, 0, 0);
      }
    PHASE_END

#pragma unroll
    for (int n = 0; n < 2; n++) {
      const int r = (wn * 64 + (n + 2) * 16 + fr) * 32 + frsw;
      fb1[n * 2 + 0] = *(const short8*)(ls + BPAN(0, 0) + r);
      fb1[n * 2 + 1] = *(const short8*)(ls + BPAN(0, 1) + r);
    }
    STG_A(APAN(1, 1), kA1 + 32);
    PHASE_MID
#pragma unroll
    for (int m = 0; m < 4; m++)
#pragma unroll
      for (int n = 0; n < 2; n++) {
        acc[m][n+2] = __builtin_amdgcn_mfma_f32_16x16x32_bf16(fa0[m*2+0], fb1[n*2+0], acc[m][n+2], 0, 0, 0);
        acc[m][n+2] = __builtin_amdgcn_mfma_f32_16x16x32_bf16(fa0[m*2+1], fb1[n*2+1], acc[m][n+2], 0, 0, 0);
      }
    PHASE_END

#pragma unroll
    for (int m = 0; m < 4; m++) {
      const int r = (wm * 128 + (m + 4) * 16 + fr) * 32 + frsw;
      fa1[m * 2 + 0] = *(const short8*)(ls + APAN(0, 0) + r);
      fa1[m * 2 + 1] = *(const short8*)(ls + APAN(0, 1) + r);
    }
    if (more) STG_B(BPAN(0, 0), kE2);
    PHASE_MID
#pragma unroll
    for (int m = 0; m < 4; m++)
#pragma unroll
      for (int n = 0; n < 2; n++) {
        acc[m+4][n] = __builtin_amdgcn_mfma_f32_16x16x32_bf16(fa1[m*2+0], fb0[n*2+0], acc[m+4][n], 0, 0, 0);
        acc[m+4][n] = __builtin_amdgcn_mfma_f32_16x16x32_bf16(fa1[m*2+1], fb0[n*2+1], acc[m+4][n], 0, 0, 0);
      }
    PHASE_END

    if (more) STG_B(BPAN(0, 1), kE2 + 32);
    PHASE_MID
#pragma unroll
    for (int m = 0; m < 4; m++)
#pragma unroll
      for (int n = 0; n < 2; n++) {
        acc[m+4][n+2] = __builtin_amdgcn_mfma_f32_16x16x32_bf16(fa1[m*2+0], fb1[n*2+0], acc[m+4][n+2], 0, 0, 0);
        acc[m+4][n+2] = __builtin_amdgcn_mfma_f32_16x16x32_bf16(fa1[m*2+1], fb1[n*2+1], acc[m+4][n+2], 0, 0, 0);
      }
    __builtin_amdgcn_s_setprio(0);
    if (more) { WAIT_VM(4); } else { WAIT_VM(0); }
    __builtin_amdgcn_s_barrier();

#pragma unroll
    for (int m = 0; m < 4; m++) {
      const int r = (wm * 128 + m * 16 + fr) * 32 + frsw;
      fa0[m * 2 + 0] = *(const short8*)(ls + APAN(1, 0) + r);
      fa0[m * 2 + 1] = *(const short8*)(ls + APAN(1, 1) + r);
    }
#pragma unroll
    for (int n = 0; n < 2; n++) {
      const int r = (wn * 64 + n * 16 + fr) * 32 + frsw;
      fb0[n * 2 + 0] = *(const short8*)(ls + BPAN(1, 0) + r);
      fb0[n * 2 + 1] = *(const short8*)(ls + BPAN(1, 1) + r);
    }
    if (more) STG_A(APAN(0, 0), kE2);
    PHASE_MID
#pragma unroll
    for (int m = 0; m < 4; m++)
#pragma unroll
      for (int n = 0; n < 2; n++) {
        acc[m][n] = __builtin_amdgcn_mfma_f32_16x16x32_bf16(fa0[m*2+0], fb0[n*2+0], acc[m][n], 0, 0, 0);
        acc[m][n] = __builtin_amdgcn_mfma_f32_16x16x32_bf16(fa0[m*2+1], fb0[n*2+1], acc[m][n], 0, 0, 0);
      }
    PHASE_END

#pragma unroll
    for (int n = 0; n < 2; n++) {
      const int r = (wn * 64 + (n + 2) * 16 + fr) * 32 + frsw;
      fb1[n * 2 + 0] = *(const short8*)(ls + BPAN(1, 0) + r);
      fb1[n * 2 + 1] = *(const short8*)(ls + BPAN(1, 1) + r);
    }
    if (more) STG_A(APAN(0, 1), kE2 + 32);
    PHASE_MID
#pragma unroll
    for (int m = 0; m < 4; m++)
#pragma unroll
      for (int n = 0; n < 2; n++) {
        acc[m][n+2] = __builtin_amdgcn_mfma_f32_16x16x32_bf16(fa0[m*2+0], fb1[n*2+0], acc[m][n+2], 0, 0, 0);
        acc[m][n+2] = __builtin_amdgcn_mfma_f32_16x16x32_bf16(fa0[m*2+1], fb1[n*2+1], acc[m][n+2], 0, 0, 0);
      }
    PHASE_END

#pragma unroll
    for (int m = 0; m < 4; m++) {
      const int r = (wm * 128 + (m + 4) * 16 + fr) * 32 + frsw;
      fa1[m * 2 + 0] = *(const short8*)(ls + APAN(1, 0) + r);
      fa1[m * 2 + 1] = *(const short8*)(ls + APAN(1, 1) + r);
    }
    if (more) STG_B(BPAN(1, 0), kO3);
    PHASE_MID
#pragma unroll
    for (int m = 0; m < 4; m++)
#pragma unroll
      for (int n = 0; n < 2; n++) {
        acc[m+4][n] = __builtin_amdgcn_mfma_f32_16x16x32_bf16(fa1[m*2+0], fb0[n*2+0], acc[m+4][n], 0, 0, 0);
        acc[m+4][n] = __builtin_amdgcn_mfma_f32_16x16x32_bf16(fa1[m*2+1], fb0[n*2+1], acc[m+4][n], 0, 0, 0);
      }
    PHASE_END

    if (more) STG_B(BPAN(1, 1), kO3 + 32);
    PHASE_MID
#pragma unroll
    for (int m = 0; m < 4; m++)
#pragma unroll
      for (int n = 0; n < 2; n++) {
        acc[m+4][n+2] = __builtin_amdgcn_mfma_f32_16x16x32_bf16(fa1[m*2+0], fb1[n*2+0], acc[m+4][n+2], 0, 0, 0);
        acc[m+4][n+2] = __builtin_amdgcn_mfma_f32_16x16x32_bf16(fa1[m*2+1], fb1[n*2+1], acc[m+4][n+2], 0, 0, 0);
      }
    __builtin_amdgcn_s_setprio(0);
    if (more) { WAIT_VM(4); }
    __builtin_amdgcn_s_barrier();
  }

#pragma unroll
  for (int mi = 0; mi < 8; mi++) {
    const size_t row0 = rowBase + wm * 128 + mi * 16 + kq4 * 4;
#pragma unroll
    for (int ni = 0; ni < 4; ni++) {
      const int col = (int)colBase + wn * 64 + ni * 16 + fr;
      const float bv = bias[col];
#pragma unroll
      for (int j = 0; j < 4; j++) {
        float x = acc[mi][ni][j] + bv;
        C[(row0 + j) * (size_t)N + col] = f2bf(x);
      }
    }
  }
}

// ---------------------------------------------------------------- fp8 gate GEMM, frag-blocked LDS (conflict-free by construction)
// Panels 8 KB (one 256x32 fp8 tile in frag order). Stage: thread tid copies
// 16 B at src kt*8192 + tid*16 (linear). Read: lane (fr,kq4) frag grp:
// pan + grp*512 + kq4*128 + fr*8 — each 16-lane quarter = contiguous 128 B
// = all 32 banks -> 0 conflicts. vmcnt(2) at ph4/ph8.
__global__ __launch_bounds__(512, 2)
void gemm_gate8(const unsigned char* __restrict__ A,
                const unsigned char* __restrict__ W,
                const float* __restrict__ bias,
                const float* __restrict__ w2, float* __restrict__ egp, int rowsTot) {
  __shared__ unsigned char ls[65536];
  const int tid  = threadIdx.x;
  const int lane = tid & 63;
  const int wave = tid >> 6;
  const int wm = wave >> 2, wn = wave & 3;
  const int fr = lane & 15, kq4 = lane >> 4;

  const int nwg = gridDim.x * gridDim.y;   // 512
  const int lin = blockIdx.y * gridDim.x + blockIdx.x;
  const int cpx = nwg >> 3;
  const int nid = (lin & 7) * cpx + (lin >> 3);
  const int bx = nid % gridDim.x, by = nid / gridDim.x;
  const size_t rowBase = (size_t)by * 256;
  const size_t colBase = (size_t)bx * 256;

  const int NTT = CMBD >> 6;               // 48

  f32x4 acc[8][4];
#pragma unroll
  for (int mi = 0; mi < 8; mi++)
#pragma unroll
    for (int ni = 0; ni < 4; ni++) acc[mi][ni] = (f32x4){0.f, 0.f, 0.f, 0.f};

  const int lp = kq4 * 128 + fr * 8;       // lane part of read addr

  const unsigned char* gA = A + (size_t)by * 786432 + tid * 16;
  const unsigned char* gB = W + (size_t)bx * 786432 + tid * 16;
  unsigned char* const sdst = ls + tid * 16;

  auto STG_A = [&](int panOff, int kt) {
    __builtin_amdgcn_global_load_lds((gvoid_t*)(gA + (size_t)kt * 8192), (lvoid_t*)(sdst + panOff), 16, 0, 0);
  };
  auto STG_B = [&](int panOff, int kt) {
    __builtin_amdgcn_global_load_lds((gvoid_t*)(gB + (size_t)kt * 8192), (lvoid_t*)(sdst + 32768 + panOff), 16, 0, 0);
  };

  // prologue: tile0 A+B (kt 0,1), tile1 B (kt 2,3)
  STG_A(APAN(0, 0), 0); STG_A(APAN(0, 1), 1);
  STG_B(APAN(0, 0), 0); STG_B(APAN(0, 1), 1);
  STG_B(APAN(1, 0), 2); STG_B(APAN(1, 1), 3);
  WAIT_VM(2);
  __builtin_amdgcn_s_barrier();

  long long fa0[8], fa1[8], fb0[4], fb1[4];

  for (int t = 0; t < NTT; t += 2) {
    const bool more = (t + 2 < NTT);
    const int k1 = 2 * (t + 1), k2 = 2 * (t + 2), k3 = 2 * (t + 3);

    // ===== even half: buf0 (tile t) =====
#pragma unroll
    for (int m = 0; m < 4; m++) {
      const int r = (wm * 8 + m) * 512 + lp;
      fa0[m * 2 + 0] = *(const long long*)(ls + APAN(0, 0) + r);
      fa0[m * 2 + 1] = *(const long long*)(ls + APAN(0, 1) + r);
    }
#pragma unroll
    for (int n = 0; n < 2; n++) {
      const int r = 32768 + (wn * 4 + n) * 512 + lp;
      fb0[n * 2 + 0] = *(const long long*)(ls + APAN(0, 0) + r);
      fb0[n * 2 + 1] = *(const long long*)(ls + APAN(0, 1) + r);
    }
    STG_A(APAN(1, 0), k1);
    PHASE_MID
#pragma unroll
    for (int m = 0; m < 4; m++)
#pragma unroll
      for (int n = 0; n < 2; n++) {
        acc[m][n] = __builtin_amdgcn_mfma_f32_16x16x32_fp8_fp8(fa0[m*2+0], fb0[n*2+0], acc[m][n], 0, 0, 0);
        acc[m][n] = __builtin_amdgcn_mfma_f32_16x16x32_fp8_fp8(fa0[m*2+1], fb0[n*2+1], acc[m][n], 0, 0, 0);
      }
    PHASE_END

#pragma unroll
    for (int n = 0; n < 2; n++) {
      const int r = 32768 + (wn * 4 + n + 2) * 512 + lp;
      fb1[n * 2 + 0] = *(const long long*)(ls + APAN(0, 0) + r);
      fb1[n * 2 + 1] = *(const long long*)(ls + APAN(0, 1) + r);
    }
    STG_A(APAN(1, 1), k1 + 1);
    PHASE_MID
#pragma unroll
    for (int m = 0; m < 4; m++)
#pragma unroll
      for (int n = 0; n < 2; n++) {
        acc[m][n+2] = __builtin_amdgcn_mfma_f32_16x16x32_fp8_fp8(fa0[m*2+0], fb1[n*2+0], acc[m][n+2], 0, 0, 0);
        acc[m][n+2] = __builtin_amdgcn_mfma_f32_16x16x32_fp8_fp8(fa0[m*2+1], fb1[n*2+1], acc[m][n+2], 0, 0, 0);
      }
    PHASE_END

#pragma unroll
    for (int m = 0; m < 4; m++) {
      const int r = (wm * 8 + m + 4) * 512 + lp;
      fa1[m * 2 + 0] = *(const long long*)(ls + APAN(0, 0) + r);
      fa1[m * 2 + 1] = *(const long long*)(ls + APAN(0, 1) + r);
    }
    if (more) STG_B(APAN(0, 0), k2);
    PHASE_MID
#pragma unroll
    for (int m = 0; m < 4; m++)
#pragma unroll
      for (int n = 0; n < 2; n++) {
        acc[m+4][n] = __builtin_amdgcn_mfma_f32_16x16x32_fp8_fp8(fa1[m*2+0], fb0[n*2+0], acc[m+4][n], 0, 0, 0);
        acc[m+4][n] = __builtin_amdgcn_mfma_f32_16x16x32_fp8_fp8(fa1[m*2+1], fb0[n*2+1], acc[m+4][n], 0, 0, 0);
      }
    PHASE_END

    if (more) STG_B(APAN(0, 1), k2 + 1);
    PHASE_MID
#pragma unroll
    for (int m = 0; m < 4; m++)
#pragma unroll
      for (int n = 0; n < 2; n++) {
        acc[m+4][n+2] = __builtin_amdgcn_mfma_f32_16x16x32_fp8_fp8(fa1[m*2+0], fb1[n*2+0], acc[m+4][n+2], 0, 0, 0);
        acc[m+4][n+2] = __builtin_amdgcn_mfma_f32_16x16x32_fp8_fp8(fa1[m*2+1], fb1[n*2+1], acc[m+4][n+2], 0, 0, 0);
      }
    __builtin_amdgcn_s_setprio(0);
    if (more) { WAIT_VM(2); } else { WAIT_VM(0); }
    __builtin_amdgcn_s_barrier();

    // ===== odd half: buf1 (tile t+1) =====
#pragma unroll
    for (int m = 0; m < 4; m++) {
      const int r = (wm * 8 + m) * 512 + lp;
      fa0[m * 2 + 0] = *(const long long*)(ls + APAN(1, 0) + r);
      fa0[m * 2 + 1] = *(const long long*)(ls + APAN(1, 1) + r);
    }
#pragma unroll
    for (int n = 0; n < 2; n++) {
      const int r = 32768 + (wn * 4 + n) * 512 + lp;
      fb0[n * 2 + 0] = *(const long long*)(ls + APAN(1, 0) + r);
      fb0[n * 2 + 1] = *(const long long*)(ls + APAN(1, 1) + r);
    }
    if (more) STG_A(APAN(0, 0), k2);
    PHASE_MID
#pragma unroll
    for (int m = 0; m < 4; m++)
#pragma unroll
      for (int n = 0; n < 2; n++) {
        acc[m][n] = __builtin_amdgcn_mfma_f32_16x16x32_fp8_fp8(fa0[m*2+0], fb0[n*2+0], acc[m][n], 0, 0, 0);
        acc[m][n] = __builtin_amdgcn_mfma_f32_16x16x32_fp8_fp8(fa0[m*2+1], fb0[n*2+1], acc[m][n], 0, 0, 0);
      }
    PHASE_END

#pragma unroll
    for (int n = 0; n < 2; n++) {
      const int r = 32768 + (wn * 4 + n + 2) * 512 + lp;
      fb1[n * 2 + 0] = *(const long long*)(ls + APAN(1, 0) + r);
      fb1[n * 2 + 1] = *(const long long*)(ls + APAN(1, 1) + r);
    }
    if (more) STG_A(APAN(0, 1), k2 + 1);
    PHASE_MID
#pragma unroll
    for (int m = 0; m < 4; m++)
#pragma unroll
      for (int n = 0; n < 2; n++) {
        acc[m][n+2] = __builtin_amdgcn_mfma_f32_16x16x32_fp8_fp8(fa0[m*2+0], fb1[n*2+0], acc[m][n+2], 0, 0, 0);
        acc[m][n+2] = __builtin_amdgcn_mfma_f32_16x16x32_fp8_fp8(fa0[m*2+1], fb1[n*2+1], acc[m][n+2], 0, 0, 0);
      }
    PHASE_END

#pragma unroll
    for (int m = 0; m < 4; m++) {
      const int r = (wm * 8 + m + 4) * 512 + lp;
      fa1[m * 2 + 0] = *(const long long*)(ls + APAN(1, 0) + r);
      fa1[m * 2 + 1] = *(const long long*)(ls + APAN(1, 1) + r);
    }
    if (more) STG_B(APAN(1, 0), k3);
    PHASE_MID
#pragma unroll
    for (int m = 0; m < 4; m++)
#pragma unroll
      for (int n = 0; n < 2; n++) {
        acc[m+4][n] = __builtin_amdgcn_mfma_f32_16x16x32_fp8_fp8(fa1[m*2+0], fb0[n*2+0], acc[m+4][n], 0, 0, 0);
        acc[m+4][n] = __builtin_amdgcn_mfma_f32_16x16x32_fp8_fp8(fa1[m*2+1], fb0[n*2+1], acc[m+4][n], 0, 0, 0);
      }
    PHASE_END

    if (more) STG_B(APAN(1, 1), k3 + 1);
    PHASE_MID
#pragma unroll
    for (int m = 0; m < 4; m++)
#pragma unroll
      for (int n = 0; n < 2; n++) {
        acc[m+4][n+2] = __builtin_amdgcn_mfma_f32_16x16x32_fp8_fp8(fa1[m*2+0], fb1[n*2+0], acc[m+4][n+2], 0, 0, 0);
        acc[m+4][n+2] = __builtin_amdgcn_mfma_f32_16x16x32_fp8_fp8(fa1[m*2+1], fb1[n*2+1], acc[m+4][n+2], 0, 0, 0);
      }
    __builtin_amdgcn_s_setprio(0);
    if (more) { WAIT_VM(2); }
    __builtin_amdgcn_s_barrier();
  }

  // fused gate epilogue
  float w2v[4], bvv[4];
#pragma unroll
  for (int ni = 0; ni < 4; ni++) {
    const int c = (int)colBase + wn * 64 + ni * 16 + fr;
    w2v[ni] = w2[c]; bvv[ni] = bias[c];
  }
  const int half = (colBase >= 1024) ? 1 : 0;
#pragma unroll
  for (int mi = 0; mi < 8; mi++) {
    float sj[4] = {0.f, 0.f, 0.f, 0.f};
#pragma unroll
    for (int ni = 0; ni < 4; ni++)
#pragma unroll
      for (int j = 0; j < 4; j++) {
        float x = acc[mi][ni][j] + bvv[ni];
        float g = 0.5f * x * (1.f + erff(x * 0.70710678118f));
        sj[j] += g * w2v[ni];
      }
#pragma unroll
    for (int j = 0; j < 4; j++) {
#pragma unroll
      for (int o = 8; o >= 1; o >>= 1) sj[j] += __shfl_xor(sj[j], o);
      if (fr == 0) {
        const int row = (int)rowBase + wm * 128 + mi * 16 + kq4 * 4 + j;
        atomicAdd(egp + half * rowsTot + row, sj[j]);
      }
    }
  }
}

// ---------------------------------------------------------------- block reduces
__device__ inline float4 block_sum4(float a, float b, float c, float d, float* sc) {
#pragma unroll
  for (int o = 32; o >= 1; o >>= 1) {
    a += __shfl_down(a, o); b += __shfl_down(b, o);
    c += __shfl_down(c, o); d += __shfl_down(d, o);
  }
  const int lane = threadIdx.x & 63, w = threadIdx.x >> 6;
  const int nw = blockDim.x >> 6;
  if (lane == 0) { sc[w*4] = a; sc[w*4+1] = b; sc[w*4+2] = c; sc[w*4+3] = d; }
  __syncthreads();
  float ra = 0.f, rb = 0.f, rc = 0.f, rd = 0.f;
  for (int i = 0; i < nw; i++) { ra += sc[i*4]; rb += sc[i*4+1]; rc += sc[i*4+2]; rd += sc[i*4+3]; }
  __syncthreads();
  return make_float4(ra, rb, rc, rd);
}
__device__ inline float2 block_sum2(float a, float b, float* sc) {
#pragma unroll
  for (int o = 32; o >= 1; o >>= 1) { a += __shfl_down(a, o); b += __shfl_down(b, o); }
  const int lane = threadIdx.x & 63, w = threadIdx.x >> 6;
  const int nw = blockDim.x >> 6;
  if (lane == 0) { sc[w*2] = a; sc[w*2+1] = b; }
  __syncthreads();
  float ra = 0.f, rb = 0.f;
  for (int i = 0; i < nw; i++) { ra += sc[i*2]; rb += sc[i*2+1]; }
  __syncthreads();
  return make_float2(ra, rb);
}

// ---------------------------------------------------------------- fused LN(q),LN(k) + 16x16 attention
__global__ __launch_bounds__(256)
void attn_ln(const short* __restrict__ qp, const short* __restrict__ kv,
             const float* __restrict__ lnqw, const float* __restrict__ lnqb,
             const float* __restrict__ lnkw, const float* __restrict__ lnkb,
             short* __restrict__ att) {
  __shared__ float qs[HID];
  __shared__ float ks[NH * 65];
  __shared__ float vs[HID];
  __shared__ float aw[256];
  __shared__ float red[16];
  const int t = threadIdx.x;
  const size_t row = blockIdx.x;

  short4v q4 = *(const short4v*)(qp + row * HID + t * 4);
  short4v k4 = *(const short4v*)(kv + row * 2048 + t * 4);
  short4v v4 = *(const short4v*)(kv + row * 2048 + 1024 + t * 4);
  float qv[4], kvv[4];
  float sq = 0.f, sqq = 0.f, sk = 0.f, skk = 0.f;
#pragma unroll
  for (int i = 0; i < 4; i++) {
    qv[i] = bf2f(q4[i]); sq += qv[i]; sqq += qv[i] * qv[i];
    kvv[i] = bf2f(k4[i]); sk += kvv[i]; skk += kvv[i] * kvv[i];
  }
  float4 r4 = block_sum4(sq, sqq, sk, skk, red);
  float mq = r4.x / HID, vq = r4.y / HID - mq * mq;
  float rsq = rsqrtf(vq + 1e-5f);
  float mk = r4.z / HID, vv = r4.w / HID - mk * mk;
  float rsk = rsqrtf(vv + 1e-5f);
#pragma unroll
  for (int i = 0; i < 4; i++) {
    const int idx = t * 4 + i;
    qs[idx] = (qv[i] - mq) * rsq * lnqw[idx] + lnqb[idx];
    ks[(idx >> 6) * 65 + (idx & 63)] = (kvv[i] - mk) * rsk * lnkw[idx] + lnkb[idx];
    vs[idx] = bf2f(v4[i]);
  }
  __syncthreads();

  const int h = t >> 4, j = t & 15;
  float s = 0.f;
#pragma unroll 8
  for (int d = 0; d < 64; d++) s += qs[h * 64 + d] * ks[j * 65 + d];
  s *= 0.125f;
  float mx = s;
#pragma unroll
  for (int o = 8; o >= 1; o >>= 1) mx = fmaxf(mx, __shfl_xor(mx, o, 16));
  float e = __expf(s - mx);
  float sum = e;
#pragma unroll
  for (int o = 8; o >= 1; o >>= 1) sum += __shfl_xor(sum, o, 16);
  aw[t] = e / sum;
  __syncthreads();

  const int dB = (t & 15) * 4;
  float o0 = 0.f, o1 = 0.f, o2 = 0.f, o3 = 0.f;
#pragma unroll
  for (int jj = 0; jj < 16; jj++) {
    const float w = aw[h * 16 + jj];
    const float* vp = &vs[jj * 64 + dB];
    o0 += w * vp[0]; o1 += w * vp[1]; o2 += w * vp[2]; o3 += w * vp[3];
  }
  short4v o4;
  o4[0] = f2bf(o0); o4[1] = f2bf(o1); o4[2] = f2bf(o2); o4[3] = f2bf(o3);
  *(short4v*)(att + row * HID + h * 64 + dB) = o4;
}

// ---------------------------------------------------------------- final
__global__ __launch_bounds__(256)
void final_kernel(const short* __restrict__ opre, const short* __restrict__ cmb,
                  const float* __restrict__ egp, int rowsTot,
                  const float* __restrict__ bg2, const float* __restrict__ bc2,
                  const float* __restrict__ lnow, const float* __restrict__ lnob,
                  float* __restrict__ out) {
  __shared__ float red[8];
  const int t = threadIdx.x;
  const size_t row = blockIdx.x;
  short8 o8 = *(const short8*)(opre + row * QD + t * 8);
  short8 q8 = *(const short8*)(cmb + row * CMBD + t * 8);
  float x[8];
  float s = 0.f, ss = 0.f;
#pragma unroll
  for (int i = 0; i < 8; i++) { x[i] = bf2f(o8[i]); s += x[i]; ss += x[i] * x[i]; }
  float2 r = block_sum2(s, ss, red);
  float m = r.x / QD, v = r.y / QD - m * m;
  float rs = rsqrtf(v + 1e-5f);
  float gg = 1.f / (1.f + __expf(-(egp[row] + bg2[0])));
  float gc = 1.f / (1.f + __expf(-(egp[rowsTot + row] + bc2[0])));
  float g = gg * gc;
  float4v oa, ob;
#pragma unroll
  for (int i = 0; i < 8; i++) {
    const int c = t * 8 + i;
    float y = (x[i] - m) * rs * lnow[c] + lnob[c];
    float r2 = bf2f(q8[i]) + g * y;
    if (i < 4) oa[i] = r2; else ob[i - 4] = r2;
  }
  *(float4v*)(out + row * QD + t * 8) = oa;
  *(float4v*)(out + row * QD + t * 8 + 4) = ob;
}

// ---------------------------------------------------------------- launch
extern "C" void kernel_launch(void* const* d_in, const int* in_sizes, int n_in,
                              void* d_out, int out_size, void* d_ws, size_t ws_size,
                              hipStream_t stream) {
  const float* qf   = (const float*)d_in[0];
  const float* kf   = (const float*)d_in[1];
  const float* Wq   = (const float*)d_in[2];
  const float* bq   = (const float*)d_in[3];
  const float* lnqw = (const float*)d_in[4];
  const float* lnqb = (const float*)d_in[5];
  const float* Wk   = (const float*)d_in[6];
  const float* bk   = (const float*)d_in[7];
  const float* lnkw = (const float*)d_in[8];
  const float* lnkb = (const float*)d_in[9];
  const float* Wvk  = (const float*)d_in[12];
  const float* bvk  = (const float*)d_in[13];
  const float* Wo   = (const float*)d_in[14];
  const float* bo   = (const float*)d_in[15];
  const float* lnow = (const float*)d_in[16];
  const float* lnob = (const float*)d_in[17];
  const float* Wg1  = (const float*)d_in[18];
  const float* bg1  = (const float*)d_in[19];
  const float* Wg2  = (const float*)d_in[20];
  const float* bg2  = (const float*)d_in[21];
  const float* Wc1  = (const float*)d_in[22];
  const float* bc1  = (const float*)d_in[23];
  const float* Wc2  = (const float*)d_in[24];
  const float* bc2  = (const float*)d_in[25];

  const int rows = in_sizes[0] / QD;   // 16384

  char* ws = (char*)d_ws;
  size_t off = 0;
  auto alloc = [&](size_t bytes) -> char* {
    char* p = ws + off;
    off += (bytes + 255) & ~(size_t)255;
    return p;
  };
  short* cmb  = (short*)alloc((size_t)rows * CMBD * 2);
  short* wqb  = (short*)alloc((size_t)HID * QD * 2);
  short* wkv  = (short*)alloc((size_t)2 * HID * KD * 2);
  short* wob  = (short*)alloc((size_t)QD * HID * 2);
  unsigned char* wgc8 = (unsigned char*)alloc((size_t)2 * HID * CMBD);
  short* hgc  = (short*)alloc((size_t)rows * 2048 * 2);   // att; cmb8 aliases
  short* qp   = (short*)alloc((size_t)rows * HID * 2);
  short* kvp  = (short*)alloc((size_t)rows * 2048 * 2);
  float* egp  = (float*)alloc((size_t)2 * rows * 4);
  float* bgc  = (float*)alloc(2048 * 4);
  float* bkv  = (float*)alloc(2048 * 4);
  float* w2gc = (float*)alloc(2048 * 4);
  short* att  = hgc;
  unsigned char* cmb8 = (unsigned char*)hgc;  // gate reads before attn_ln writes att
  short* opre = kvp;

  const int egpN = 2 * rows;
  pack_params<<<(egpN + 6144) / 256, 256, 0, stream>>>(egp, egpN, bg1, bc1, bk, bvk,
                                                       Wg2, Wc2, bgc, bkv, w2gc);

  const int qblocks = rows * QD / 8 / 256;      // 16384
  const int kblocks = rows * KD / 8 / 256;      // 8192
  cvt_inputs<<<qblocks + kblocks, 256, 0, stream>>>(qf, kf, cmb, cmb8, qblocks);
  {
    WSeg s0{Wq,  wqb,                    2048};
    WSeg s1{Wk,  wkv,                    2048 + 1024};
    WSeg s2{Wvk, wkv + (size_t)HID * KD, 2048 + 2048};
    WSeg s3{Wo,  wob,                    2048 + 2048 + 2048};
    cvt_weights<<<s3.blkEnd, 256, 0, stream>>>(s0, s1, s2, s3);
  }
  cvt_w8<<<dim3(96, 8), 256, 0, stream>>>(Wg1, Wc1, wgc8);

  hipFuncSetAttribute((const void*)gemm256<EPI_NONE>,
                      hipFuncAttributeMaxDynamicSharedMemorySize, 131072);

  const dim3 blk(512);
  const int mt = rows / 256;   // 64
  const size_t lds = 131072;

  gemm_gate8<<<dim3(8, mt), blk, 0, stream>>>(cmb8, wgc8, bgc, w2gc, egp, rows);
  gemm256<EPI_NONE><<<dim3(1024 / 256, mt), blk, lds, stream>>>(cmb, CMBD, wqb, bq, qp, 1024, QD, nullptr, nullptr, 0);
  gemm256<EPI_NONE><<<dim3(2048 / 256, mt), blk, lds, stream>>>(cmb + QD, CMBD, wkv, bkv, kvp, 2048, KD, nullptr, nullptr, 0);
  attn_ln<<<rows, 256, 0, stream>>>(qp, kvp, lnqw, lnqb, lnkw, lnkb, att);
  gemm256<EPI_NONE><<<dim3(2048 / 256, mt), blk, lds, stream>>>(att, HID, wob, bo, opre, 2048, HID, nullptr, nullptr, 0);
  final_kernel<<<rows, 256, 0, stream>>>(opre, cmb, egp, rows, bg2, bc2, lnow, lnob, (float*)d_out);
}

// Round 21
// 578.839 us; speedup vs baseline: 1.0933x; 1.0933x over previous
//
#include <hip/hip_runtime.h>
#include <stdint.h>

#define QD 2048
#define KD 1024
#define HID 1024
#define NH 16
#define HD 64
#define CMBD 3072   // QD + KD

typedef float  f32x4   __attribute__((ext_vector_type(4)));
typedef short  short8  __attribute__((ext_vector_type(8)));
typedef short  short4v __attribute__((ext_vector_type(4)));
typedef float  float4v __attribute__((ext_vector_type(4)));

__device__ inline float bf2f(short s) {
  unsigned u = ((unsigned)(unsigned short)s) << 16;
  return __builtin_bit_cast(float, u);
}
__device__ inline short f2bf(float f) {
  unsigned u = __builtin_bit_cast(unsigned, f);
  u = u + 0x7fff + ((u >> 16) & 1);
  return (short)(u >> 16);
}
// e4m3fn (OCP), RNE, saturating
__device__ inline unsigned char f2f8(float f) {
  unsigned u = __builtin_bit_cast(unsigned, f);
  unsigned s = (u >> 24) & 0x80u;
  float a = fabsf(f);
  if (a >= 448.f) return (unsigned char)(s | 0x7E);
  if (a < 0.015625f) {
    int m = (int)(a * 512.f + 0.5f);
    if (m > 7) return (unsigned char)(s | 0x08);
    return (unsigned char)(s | m);
  }
  int ebits = (int)((u >> 23) & 0xFF) - 127;
  unsigned mant = u & 0x7FFFFF;
  unsigned keep = mant >> 20;
  unsigned rest = mant & 0xFFFFF;
  keep += (rest > 0x80000u) || (rest == 0x80000u && (keep & 1));
  if (keep == 8) { keep = 0; ebits += 1; }
  if (ebits > 8) return (unsigned char)(s | 0x7E);
  return (unsigned char)(s | ((unsigned)(ebits + 7) << 3) | keep);
}

// fp8 frag-blocked layout: addr(r,k) = (r>>8)*786432 + (k>>5)*8192 +
//   ((r>>4)&15)*512 + ((k>>3)&3)*128 + (r&15)*8 + (k&7)
__device__ inline size_t fp8addr(int r, int k) {
  return (size_t)(r >> 8) * 786432 + (size_t)(k >> 5) * 8192 +
         (size_t)((r >> 4) & 15) * 512 + (size_t)((k >> 3) & 3) * 128 +
         (size_t)(r & 15) * 8;
}

// ---------------------------------------------------------------- conversions
// Block = 16 rows x 128 cols; row = t>>4, col = (t&15)*8.
// Source reads coalesced (16-lane group = 512 B of one row); fp8 writes land
// 16 regions x 32 B per wave, adjacent waves fill the same 128-B frag blocks
// (R20's 1-row/block mapping scattered 8-B stores 128 B apart: +60 us).
__global__ void cvt_inputs(const float* __restrict__ qf, const float* __restrict__ kf,
                           short* __restrict__ cmb, unsigned char* __restrict__ cmb8,
                           int qblocks) {
  const int b = blockIdx.x, t = threadIdx.x;
  int r, k;
  const float* src;
  if (b < qblocks) {
    const int rb = b >> 4, kb = b & 15;      // QD/128 = 16 col-blocks
    r = rb * 16 + (t >> 4); k = kb * 128 + (t & 15) * 8;
    src = qf + (size_t)r * QD + k;
  } else {
    const int b2 = b - qblocks;
    const int rb = b2 >> 3, kb = b2 & 7;     // KD/128 = 8 col-blocks
    r = rb * 16 + (t >> 4); k = kb * 128 + (t & 15) * 8;
    src = kf + (size_t)r * KD + k;
    k += QD;
  }
  float4v v0 = *(const float4v*)src;
  float4v v1 = *(const float4v*)(src + 4);
  short8 o;
  o[0] = f2bf(v0[0]); o[1] = f2bf(v0[1]); o[2] = f2bf(v0[2]); o[3] = f2bf(v0[3]);
  o[4] = f2bf(v1[0]); o[5] = f2bf(v1[1]); o[6] = f2bf(v1[2]); o[7] = f2bf(v1[3]);
  *(short8*)(cmb + (size_t)r * CMBD + k) = o;
  unsigned long long p =
      (unsigned long long)f2f8(v0[0])        | ((unsigned long long)f2f8(v0[1]) << 8)  |
      ((unsigned long long)f2f8(v0[2]) << 16)| ((unsigned long long)f2f8(v0[3]) << 24) |
      ((unsigned long long)f2f8(v1[0]) << 32)| ((unsigned long long)f2f8(v1[1]) << 40) |
      ((unsigned long long)f2f8(v1[2]) << 48)| ((unsigned long long)f2f8(v1[3]) << 56);
  *(unsigned long long*)(cmb8 + fp8addr(r, k)) = p;
}

struct WSeg { const float* s; short* d; int blkEnd; };
__global__ void cvt_weights(WSeg s0, WSeg s1, WSeg s2, WSeg s3) {
  int b = blockIdx.x;
  WSeg seg; int base;
  if      (b < s0.blkEnd) { seg = s0; base = 0; }
  else if (b < s1.blkEnd) { seg = s1; base = s0.blkEnd; }
  else if (b < s2.blkEnd) { seg = s2; base = s1.blkEnd; }
  else                    { seg = s3; base = s2.blkEnd; }
  const size_t i = ((size_t)(b - base) * 256 + threadIdx.x) * 4;
  float4v v = *(const float4v*)(seg.s + i);
  short4v o;
  o[0] = f2bf(v[0]); o[1] = f2bf(v[1]); o[2] = f2bf(v[2]); o[3] = f2bf(v[3]);
  *(short4v*)(seg.d + i) = o;
}

// Wg1||Wc1 -> fp8 frag-blocked wgc8; grid(96 kt, 8 band), 4 pieces/thread
__global__ void cvt_w8(const float* __restrict__ Wg1, const float* __restrict__ Wc1,
                       unsigned char* __restrict__ wgc8) {
  const int kt = blockIdx.x, band = blockIdx.y;
  unsigned char* dst = wgc8 + (size_t)band * 786432 + (size_t)kt * 8192;
  for (int p = threadIdx.x; p < 1024; p += 256) {
    const int grp = p >> 6, kq = (p >> 4) & 3, fr = p & 15;
    const int c = band * 256 + grp * 16 + fr;
    const int k = kt * 32 + kq * 8;
    const float* s = (c < 1024 ? Wg1 + (size_t)c * CMBD : Wc1 + (size_t)(c - 1024) * CMBD) + k;
    float4v v0 = *(const float4v*)s;
    float4v v1 = *(const float4v*)(s + 4);
    unsigned long long pk =
        (unsigned long long)f2f8(v0[0])        | ((unsigned long long)f2f8(v0[1]) << 8)  |
        ((unsigned long long)f2f8(v0[2]) << 16)| ((unsigned long long)f2f8(v0[3]) << 24) |
        ((unsigned long long)f2f8(v1[0]) << 32)| ((unsigned long long)f2f8(v1[1]) << 40) |
        ((unsigned long long)f2f8(v1[2]) << 48)| ((unsigned long long)f2f8(v1[3]) << 56);
    *(unsigned long long*)(dst + p * 8) = pk;
  }
}

// ---------------------------------------------------------------- pack
__global__ void pack_params(float* __restrict__ egp, int egpN,
                            const float* __restrict__ bg1, const float* __restrict__ bc1,
                            const float* __restrict__ bk,  const float* __restrict__ bvk,
                            const float* __restrict__ Wg2, const float* __restrict__ Wc2,
                            float* __restrict__ bgc, float* __restrict__ bkv,
                            float* __restrict__ w2gc) {
  int i = blockIdx.x * 256 + threadIdx.x;
  if (i < egpN) { egp[i] = 0.f; return; }
  i -= egpN;
  const int seg = i >> 10, idx = i & 1023;
  switch (seg) {
    case 0: bgc[idx]         = bg1[idx]; break;
    case 1: bgc[1024 + idx]  = bc1[idx]; break;
    case 2: bkv[idx]         = bk[idx];  break;
    case 3: bkv[1024 + idx]  = bvk[idx]; break;
    case 4: w2gc[idx]        = Wg2[idx]; break;
    case 5: w2gc[1024 + idx] = Wc2[idx]; break;
  }
}

// ---------------------------------------------------------------- common GEMM defs
#define EPI_NONE 0

typedef const __attribute__((address_space(1))) void gvoid_t;
typedef __attribute__((address_space(3))) void lvoid_t;

#define WAIT_VM(n)  asm volatile("s_waitcnt vmcnt(" #n ")" ::: "memory")

#define APAN(b, kp) (((b) * 2 + (kp)) * 8192)
#define BPAN(b, kp) (32768 + ((b) * 2 + (kp)) * 8192)

#define PHASE_MID                                        \
  __builtin_amdgcn_s_barrier();                          \
  asm volatile("s_waitcnt lgkmcnt(0)" ::: "memory");     \
  __builtin_amdgcn_s_setprio(1);

#define PHASE_END                                        \
  __builtin_amdgcn_s_setprio(0);                         \
  __builtin_amdgcn_s_barrier();

// ---------------------------------------------------------------- bf16 256x256 GEMM (verified) — Q/KV/O
template<int EPI>
__global__ __launch_bounds__(512, 2)
void gemm256(const short* __restrict__ A, size_t lda,
             const short* __restrict__ W,
             const float* __restrict__ bias,
             short* __restrict__ C, int N, int K,
             const float* __restrict__ w2, float* __restrict__ egp, int rowsTot) {
  extern __shared__ short ls[];
  const int tid  = threadIdx.x;
  const int lane = tid & 63;
  const int wave = tid >> 6;
  const int wm = wave >> 2, wn = wave & 3;
  const int fr = lane & 15, kq4 = lane >> 4;

  const int nwg = gridDim.x * gridDim.y;
  const int lin = blockIdx.y * gridDim.x + blockIdx.x;
  const int cpx = nwg >> 3;
  const int nid = (lin & 7) * cpx + (lin >> 3);
  const int bx = nid % gridDim.x, by = nid / gridDim.x;
  const size_t rowBase = (size_t)by * 256;
  const size_t colBase = (size_t)bx * 256;

  const int NTT = K >> 6;

  f32x4 acc[8][4];
#pragma unroll
  for (int mi = 0; mi < 8; mi++)
#pragma unroll
    for (int ni = 0; ni < 4; ni++) acc[mi][ni] = (f32x4){0.f, 0.f, 0.f, 0.f};

  const int frsw = (kq4 ^ ((fr >> 1) & 3)) * 8;

  const int grow  = tid >> 2;
  const int slotx = (tid & 3) ^ ((tid >> 3) & 3);
  const short* gAlo = A + (rowBase + grow) * lda + slotx * 8;
  const short* gAhi = gAlo + (size_t)128 * lda;
  const short* gBlo = W + (colBase + grow) * (size_t)K + slotx * 8;
  const short* gBhi = gBlo + (size_t)128 * K;
  short* const sdst = ls + tid * 8;

  auto STG_A = [&](int panOff, int kcol) {
    __builtin_amdgcn_global_load_lds((gvoid_t*)(gAlo + kcol), (lvoid_t*)(sdst + panOff),        16, 0, 0);
    __builtin_amdgcn_global_load_lds((gvoid_t*)(gAhi + kcol), (lvoid_t*)(sdst + panOff + 4096), 16, 0, 0);
  };
  auto STG_B = [&](int panOff, int kcol) {
    __builtin_amdgcn_global_load_lds((gvoid_t*)(gBlo + kcol), (lvoid_t*)(sdst + panOff),        16, 0, 0);
    __builtin_amdgcn_global_load_lds((gvoid_t*)(gBhi + kcol), (lvoid_t*)(sdst + panOff + 4096), 16, 0, 0);
  };

  STG_A(APAN(0, 0), 0);  STG_A(APAN(0, 1), 32);
  STG_B(BPAN(0, 0), 0);  STG_B(BPAN(0, 1), 32);
  STG_B(BPAN(1, 0), 64); STG_B(BPAN(1, 1), 96);
  WAIT_VM(4);
  __builtin_amdgcn_s_barrier();

  short8 fa0[8], fa1[8], fb0[4], fb1[4];

  for (int t = 0; t < NTT; t += 2) {
    const bool more = (t + 2 < NTT);
    const int kA1 = (t + 1) * 64;
    const int kE2 = (t + 2) * 64;
    const int kO3 = (t + 3) * 64;

#pragma unroll
    for (int m = 0; m < 4; m++) {
      const int r = (wm * 128 + m * 16 + fr) * 32 + frsw;
      fa0[m * 2 + 0] = *(const short8*)(ls + APAN(0, 0) + r);
      fa0[m * 2 + 1] = *(const short8*)(ls + APAN(0, 1) + r);
    }
#pragma unroll
    for (int n = 0; n < 2; n++) {
      const int r = (wn * 64 + n * 16 + fr) * 32 + frsw;
      fb0[n * 2 + 0] = *(const short8*)(ls + BPAN(0, 0) + r);
      fb0[n * 2 + 1] = *(const short8*)(ls + BPAN(0, 1) + r);
    }
    STG_A(APAN(1, 0), kA1);
    PHASE_MID
#pragma unroll
    for (int m = 0; m < 4; m++)
#pragma unroll
      for (int n = 0; n < 2; n++) {
        acc[m][n] = __builtin_amdgcn_mfma_f32_16x16x32_bf16(fa0[m*2+0], fb0[n*2+0], acc[m][n], 0, 0, 0);
        acc[m][n] = __builtin_amdgcn_mfma_f32_16x16x32_bf16(fa0[m*2+1], fb0[n*2+1], acc[m][n], 0, 0, 0);
      }
    PHASE_END

#pragma unroll
    for (int n = 0; n < 2; n++) {
      const int r = (wn * 64 + (n + 2) * 16 + fr) * 32 + frsw;
      fb1[n * 2 + 0] = *(const short8*)(ls + BPAN(0, 0) + r);
      fb1[n * 2 + 1] = *(const short8*)(ls + BPAN(0, 1) + r);
    }
    STG_A(APAN(1, 1), kA1 + 32);
    PHASE_MID
#pragma unroll
    for (int m = 0; m < 4; m++)
#pragma unroll
      for (int n = 0; n < 2; n++) {
        acc[m][n+2] = __builtin_amdgcn_mfma_f32_16x16x32_bf16(fa0[m*2+0], fb1[n*2+0], acc[m][n+2], 0, 0, 0);
        acc[m][n+2] = __builtin_amdgcn_mfma_f32_16x16x32_bf16(fa0[m*2+1], fb1[n*2+1], acc[m][n+2], 0, 0, 0);
      }
    PHASE_END

#pragma unroll
    for (int m = 0; m < 4; m++) {
      const int r = (wm * 128 + (m + 4) * 16 + fr) * 32 + frsw;
      fa1[m * 2 + 0] = *(const short8*)(ls + APAN(0, 0) + r);
      fa1[m * 2 + 1] = *(const short8*)(ls + APAN(0, 1) + r);
    }
    if (more) STG_B(BPAN(0, 0), kE2);
    PHASE_MID
#pragma unroll
    for (int m = 0; m < 4; m++)
#pragma unroll
      for (int n = 0; n < 2; n++) {
        acc[m+4][n] = __builtin_amdgcn_mfma_f32_16x16x32_bf16(fa1[m*2+0], fb0[n*2+0], acc[m+4][n], 0, 0, 0);
        acc[m+4][n] = __builtin_amdgcn_mfma_f32_16x16x32_bf16(fa1[m*2+1], fb0[n*2+1], acc[m+4][n], 0, 0, 0);
      }
    PHASE_END

    if (more) STG_B(BPAN(0, 1), kE2 + 32);
    PHASE_MID
#pragma unroll
    for (int m = 0; m < 4; m++)
#pragma unroll
      for (int n = 0; n < 2; n++) {
        acc[m+4][n+2] = __builtin_amdgcn_mfma_f32_16x16x32_bf16(fa1[m*2+0], fb1[n*2+0], acc[m+4][n+2], 0, 0, 0);
        acc[m+4][n+2] = __builtin_amdgcn_mfma_f32_16x16x32_bf16(fa1[m*2+1], fb1[n*2+1], acc[m+4][n+2], 0, 0, 0);
      }
    __builtin_amdgcn_s_setprio(0);
    if (more) { WAIT_VM(4); } else { WAIT_VM(0); }
    __builtin_amdgcn_s_barrier();

#pragma unroll
    for (int m = 0; m < 4; m++) {
      const int r = (wm * 128 + m * 16 + fr) * 32 + frsw;
      fa0[m * 2 + 0] = *(const short8*)(ls + APAN(1, 0) + r);
      fa0[m * 2 + 1] = *(const short8*)(ls + APAN(1, 1) + r);
    }
#pragma unroll
    for (int n = 0; n < 2; n++) {
      const int r = (wn * 64 + n * 16 + fr) * 32 + frsw;
      fb0[n * 2 + 0] = *(const short8*)(ls + BPAN(1, 0) + r);
      fb0[n * 2 + 1] = *(const short8*)(ls + BPAN(1, 1) + r);
    }
    if (more) STG_A(APAN(0, 0), kE2);
    PHASE_MID
#pragma unroll
    for (int m = 0; m < 4; m++)
#pragma unroll
      for (int n = 0; n < 2; n++) {
        acc[m][n] = __builtin_amdgcn_mfma_f32_16x16x32_bf16(fa0[m*2+0], fb0[n*2+0], acc[m][n], 0, 0, 0);
        acc[m][n] = __builtin_amdgcn_mfma_f32_16x16x32_bf16(fa0[m*2+1], fb0[n*2+1], acc[m][n], 0, 0, 0);
      }
    PHASE_END

#pragma unroll
    for (int n = 0; n < 2; n++) {
      const int r = (wn * 64 + (n + 2) * 16 + fr) * 32 + frsw;
      fb1[n * 2 + 0] = *(const short8*)(ls + BPAN(1, 0) + r);
      fb1[n * 2 + 1] = *(const short8*)(ls + BPAN(1, 1) + r);
    }
    if (more) STG_A(APAN(0, 1), kE2 + 32);
    PHASE_MID
#pragma unroll
    for (int m = 0; m < 4; m++)
#pragma unroll
      for (int n = 0; n < 2; n++) {
        acc[m][n+2] = __builtin_amdgcn_mfma_f32_16x16x32_bf16(fa0[m*2+0], fb1[n*2+0], acc[m][n+2], 0, 0, 0);
        acc[m][n+2] = __builtin_amdgcn_mfma_f32_16x16x32_bf16(fa0[m*2+1], fb1[n*2+1], acc[m][n+2], 0, 0, 0);
      }
    PHASE_END

#pragma unroll
    for (int m = 0; m < 4; m++) {
      const int r = (wm * 128 + (m + 4) * 16 + fr) * 32 + frsw;
      fa1[m * 2 + 0] = *(const short8*)(ls + APAN(1, 0) + r);
      fa1[m * 2 + 1] = *(const short8*)(ls + APAN(1, 1) + r);
    }
    if (more) STG_B(BPAN(1, 0), kO3);
    PHASE_MID
#pragma unroll
    for (int m = 0; m < 4; m++)
#pragma unroll
      for (int n = 0; n < 2; n++) {
        acc[m+4][n] = __builtin_amdgcn_mfma_f32_16x16x32_bf16(fa1[m*2+0], fb0[n*2+0], acc[m+4][n], 0, 0, 0);
        acc[m+4][n] = __builtin_amdgcn_mfma_f32_16x16x32_bf16(fa1[m*2+1], fb0[n*2+1], acc[m+4][n], 0, 0, 0);
      }
    PHASE_END

    if (more) STG_B(BPAN(1, 1), kO3 + 32);
    PHASE_MID
#pragma unroll
    for (int m = 0; m < 4; m++)
#pragma unroll
      for (int n = 0; n < 2; n++) {
        acc[m+4][n+2] = __builtin_amdgcn_mfma_f32_16x16x32_bf16(fa1[m*2+0], fb1[n*2+0], acc[m+4][n+2], 0, 0, 0);
        acc[m+4][n+2] = __builtin_amdgcn_mfma_f32_16x16x32_bf16(fa1[m*2+1], fb1[n*2+1], acc[m+4][n+2], 0, 0, 0);
      }
    __builtin_amdgcn_s_setprio(0);
    if (more) { WAIT_VM(4); }
    __builtin_amdgcn_s_barrier();
  }

#pragma unroll
  for (int mi = 0; mi < 8; mi++) {
    const size_t row0 = rowBase + wm * 128 + mi * 16 + kq4 * 4;
#pragma unroll
    for (int ni = 0; ni < 4; ni++) {
      const int col = (int)colBase + wn * 64 + ni * 16 + fr;
      const float bv = bias[col];
#pragma unroll
      for (int j = 0; j < 4; j++) {
        float x = acc[mi][ni][j] + bv;
        C[(row0 + j) * (size_t)N + col] = f2bf(x);
      }
    }
  }
}

// ---------------------------------------------------------------- fp8 gate GEMM, frag-blocked LDS (R20: verified, 0 conflicts)
__global__ __launch_bounds__(512, 2)
void gemm_gate8(const unsigned char* __restrict__ A,
                const unsigned char* __restrict__ W,
                const float* __restrict__ bias,
                const float* __restrict__ w2, float* __restrict__ egp, int rowsTot) {
  __shared__ unsigned char ls[65536];
  const int tid  = threadIdx.x;
  const int lane = tid & 63;
  const int wave = tid >> 6;
  const int wm = wave >> 2, wn = wave & 3;
  const int fr = lane & 15, kq4 = lane >> 4;

  const int nwg = gridDim.x * gridDim.y;
  const int lin = blockIdx.y * gridDim.x + blockIdx.x;
  const int cpx = nwg >> 3;
  const int nid = (lin & 7) * cpx + (lin >> 3);
  const int bx = nid % gridDim.x, by = nid / gridDim.x;
  const size_t rowBase = (size_t)by * 256;
  const size_t colBase = (size_t)bx * 256;

  const int NTT = CMBD >> 6;               // 48

  f32x4 acc[8][4];
#pragma unroll
  for (int mi = 0; mi < 8; mi++)
#pragma unroll
    for (int ni = 0; ni < 4; ni++) acc[mi][ni] = (f32x4){0.f, 0.f, 0.f, 0.f};

  const int lp = kq4 * 128 + fr * 8;

  const unsigned char* gA = A + (size_t)by * 786432 + tid * 16;
  const unsigned char* gB = W + (size_t)bx * 786432 + tid * 16;
  unsigned char* const sdst = ls + tid * 16;

  auto STG_A = [&](int panOff, int kt) {
    __builtin_amdgcn_global_load_lds((gvoid_t*)(gA + (size_t)kt * 8192), (lvoid_t*)(sdst + panOff), 16, 0, 0);
  };
  auto STG_B = [&](int panOff, int kt) {
    __builtin_amdgcn_global_load_lds((gvoid_t*)(gB + (size_t)kt * 8192), (lvoid_t*)(sdst + 32768 + panOff), 16, 0, 0);
  };

  STG_A(APAN(0, 0), 0); STG_A(APAN(0, 1), 1);
  STG_B(APAN(0, 0), 0); STG_B(APAN(0, 1), 1);
  STG_B(APAN(1, 0), 2); STG_B(APAN(1, 1), 3);
  WAIT_VM(2);
  __builtin_amdgcn_s_barrier();

  long long fa0[8], fa1[8], fb0[4], fb1[4];

  for (int t = 0; t < NTT; t += 2) {
    const bool more = (t + 2 < NTT);
    const int k1 = 2 * (t + 1), k2 = 2 * (t + 2), k3 = 2 * (t + 3);

    // ===== even half: buf0 (tile t) =====
#pragma unroll
    for (int m = 0; m < 4; m++) {
      const int r = (wm * 8 + m) * 512 + lp;
      fa0[m * 2 + 0] = *(const long long*)(ls + APAN(0, 0) + r);
      fa0[m * 2 + 1] = *(const long long*)(ls + APAN(0, 1) + r);
    }
#pragma unroll
    for (int n = 0; n < 2; n++) {
      const int r = 32768 + (wn * 4 + n) * 512 + lp;
      fb0[n * 2 + 0] = *(const long long*)(ls + APAN(0, 0) + r);
      fb0[n * 2 + 1] = *(const long long*)(ls + APAN(0, 1) + r);
    }
    STG_A(APAN(1, 0), k1);
    PHASE_MID
#pragma unroll
    for (int m = 0; m < 4; m++)
#pragma unroll
      for (int n = 0; n < 2; n++) {
        acc[m][n] = __builtin_amdgcn_mfma_f32_16x16x32_fp8_fp8(fa0[m*2+0], fb0[n*2+0], acc[m][n], 0, 0, 0);
        acc[m][n] = __builtin_amdgcn_mfma_f32_16x16x32_fp8_fp8(fa0[m*2+1], fb0[n*2+1], acc[m][n], 0, 0, 0);
      }
    PHASE_END

#pragma unroll
    for (int n = 0; n < 2; n++) {
      const int r = 32768 + (wn * 4 + n + 2) * 512 + lp;
      fb1[n * 2 + 0] = *(const long long*)(ls + APAN(0, 0) + r);
      fb1[n * 2 + 1] = *(const long long*)(ls + APAN(0, 1) + r);
    }
    STG_A(APAN(1, 1), k1 + 1);
    PHASE_MID
#pragma unroll
    for (int m = 0; m < 4; m++)
#pragma unroll
      for (int n = 0; n < 2; n++) {
        acc[m][n+2] = __builtin_amdgcn_mfma_f32_16x16x32_fp8_fp8(fa0[m*2+0], fb1[n*2+0], acc[m][n+2], 0, 0, 0);
        acc[m][n+2] = __builtin_amdgcn_mfma_f32_16x16x32_fp8_fp8(fa0[m*2+1], fb1[n*2+1], acc[m][n+2], 0, 0, 0);
      }
    PHASE_END

#pragma unroll
    for (int m = 0; m < 4; m++) {
      const int r = (wm * 8 + m + 4) * 512 + lp;
      fa1[m * 2 + 0] = *(const long long*)(ls + APAN(0, 0) + r);
      fa1[m * 2 + 1] = *(const long long*)(ls + APAN(0, 1) + r);
    }
    if (more) STG_B(APAN(0, 0), k2);
    PHASE_MID
#pragma unroll
    for (int m = 0; m < 4; m++)
#pragma unroll
      for (int n = 0; n < 2; n++) {
        acc[m+4][n] = __builtin_amdgcn_mfma_f32_16x16x32_fp8_fp8(fa1[m*2+0], fb0[n*2+0], acc[m+4][n], 0, 0, 0);
        acc[m+4][n] = __builtin_amdgcn_mfma_f32_16x16x32_fp8_fp8(fa1[m*2+1], fb0[n*2+1], acc[m+4][n], 0, 0, 0);
      }
    PHASE_END

    if (more) STG_B(APAN(0, 1), k2 + 1);
    PHASE_MID
#pragma unroll
    for (int m = 0; m < 4; m++)
#pragma unroll
      for (int n = 0; n < 2; n++) {
        acc[m+4][n+2] = __builtin_amdgcn_mfma_f32_16x16x32_fp8_fp8(fa1[m*2+0], fb1[n*2+0], acc[m+4][n+2], 0, 0, 0);
        acc[m+4][n+2] = __builtin_amdgcn_mfma_f32_16x16x32_fp8_fp8(fa1[m*2+1], fb1[n*2+1], acc[m+4][n+2], 0, 0, 0);
      }
    __builtin_amdgcn_s_setprio(0);
    if (more) { WAIT_VM(2); } else { WAIT_VM(0); }
    __builtin_amdgcn_s_barrier();

    // ===== odd half: buf1 (tile t+1) =====
#pragma unroll
    for (int m = 0; m < 4; m++) {
      const int r = (wm * 8 + m) * 512 + lp;
      fa0[m * 2 + 0] = *(const long long*)(ls + APAN(1, 0) + r);
      fa0[m * 2 + 1] = *(const long long*)(ls + APAN(1, 1) + r);
    }
#pragma unroll
    for (int n = 0; n < 2; n++) {
      const int r = 32768 + (wn * 4 + n) * 512 + lp;
      fb0[n * 2 + 0] = *(const long long*)(ls + APAN(1, 0) + r);
      fb0[n * 2 + 1] = *(const long long*)(ls + APAN(1, 1) + r);
    }
    if (more) STG_A(APAN(0, 0), k2);
    PHASE_MID
#pragma unroll
    for (int m = 0; m < 4; m++)
#pragma unroll
      for (int n = 0; n < 2; n++) {
        acc[m][n] = __builtin_amdgcn_mfma_f32_16x16x32_fp8_fp8(fa0[m*2+0], fb0[n*2+0], acc[m][n], 0, 0, 0);
        acc[m][n] = __builtin_amdgcn_mfma_f32_16x16x32_fp8_fp8(fa0[m*2+1], fb0[n*2+1], acc[m][n], 0, 0, 0);
      }
    PHASE_END

#pragma unroll
    for (int n = 0; n < 2; n++) {
      const int r = 32768 + (wn * 4 + n + 2) * 512 + lp;
      fb1[n * 2 + 0] = *(const long long*)(ls + APAN(1, 0) + r);
      fb1[n * 2 + 1] = *(const long long*)(ls + APAN(1, 1) + r);
    }
    if (more) STG_A(APAN(0, 1), k2 + 1);
    PHASE_MID
#pragma unroll
    for (int m = 0; m < 4; m++)
#pragma unroll
      for (int n = 0; n < 2; n++) {
        acc[m][n+2] = __builtin_amdgcn_mfma_f32_16x16x32_fp8_fp8(fa0[m*2+0], fb1[n*2+0], acc[m][n+2], 0, 0, 0);
        acc[m][n+2] = __builtin_amdgcn_mfma_f32_16x16x32_fp8_fp8(fa0[m*2+1], fb1[n*2+1], acc[m][n+2], 0, 0, 0);
      }
    PHASE_END

#pragma unroll
    for (int m = 0; m < 4; m++) {
      const int r = (wm * 8 + m + 4) * 512 + lp;
      fa1[m * 2 + 0] = *(const long long*)(ls + APAN(1, 0) + r);
      fa1[m * 2 + 1] = *(const long long*)(ls + APAN(1, 1) + r);
    }
    if (more) STG_B(APAN(1, 0), k3);
    PHASE_MID
#pragma unroll
    for (int m = 0; m < 4; m++)
#pragma unroll
      for (int n = 0; n < 2; n++) {
        acc[m+4][n] = __builtin_amdgcn_mfma_f32_16x16x32_fp8_fp8(fa1[m*2+0], fb0[n*2+0], acc[m+4][n], 0, 0, 0);
        acc[m+4][n] = __builtin_amdgcn_mfma_f32_16x16x32_fp8_fp8(fa1[m*2+1], fb0[n*2+1], acc[m+4][n], 0, 0, 0);
      }
    PHASE_END

    if (more) STG_B(APAN(1, 1), k3 + 1);
    PHASE_MID
#pragma unroll
    for (int m = 0; m < 4; m++)
#pragma unroll
      for (int n = 0; n < 2; n++) {
        acc[m+4][n+2] = __builtin_amdgcn_mfma_f32_16x16x32_fp8_fp8(fa1[m*2+0], fb1[n*2+0], acc[m+4][n+2], 0, 0, 0);
        acc[m+4][n+2] = __builtin_amdgcn_mfma_f32_16x16x32_fp8_fp8(fa1[m*2+1], fb1[n*2+1], acc[m+4][n+2], 0, 0, 0);
      }
    __builtin_amdgcn_s_setprio(0);
    if (more) { WAIT_VM(2); }
    __builtin_amdgcn_s_barrier();
  }

  // fused gate epilogue
  float w2v[4], bvv[4];
#pragma unroll
  for (int ni = 0; ni < 4; ni++) {
    const int c = (int)colBase + wn * 64 + ni * 16 + fr;
    w2v[ni] = w2[c]; bvv[ni] = bias[c];
  }
  const int half = (colBase >= 1024) ? 1 : 0;
#pragma unroll
  for (int mi = 0; mi < 8; mi++) {
    float sj[4] = {0.f, 0.f, 0.f, 0.f};
#pragma unroll
    for (int ni = 0; ni < 4; ni++)
#pragma unroll
      for (int j = 0; j < 4; j++) {
        float x = acc[mi][ni][j] + bvv[ni];
        float g = 0.5f * x * (1.f + erff(x * 0.70710678118f));
        sj[j] += g * w2v[ni];
      }
#pragma unroll
    for (int j = 0; j < 4; j++) {
#pragma unroll
      for (int o = 8; o >= 1; o >>= 1) sj[j] += __shfl_xor(sj[j], o);
      if (fr == 0) {
        const int row = (int)rowBase + wm * 128 + mi * 16 + kq4 * 4 + j;
        atomicAdd(egp + half * rowsTot + row, sj[j]);
      }
    }
  }
}

// ---------------------------------------------------------------- block reduces
__device__ inline float4 block_sum4(float a, float b, float c, float d, float* sc) {
#pragma unroll
  for (int o = 32; o >= 1; o >>= 1) {
    a += __shfl_down(a, o); b += __shfl_down(b, o);
    c += __shfl_down(c, o); d += __shfl_down(d, o);
  }
  const int lane = threadIdx.x & 63, w = threadIdx.x >> 6;
  const int nw = blockDim.x >> 6;
  if (lane == 0) { sc[w*4] = a; sc[w*4+1] = b; sc[w*4+2] = c; sc[w*4+3] = d; }
  __syncthreads();
  float ra = 0.f, rb = 0.f, rc = 0.f, rd = 0.f;
  for (int i = 0; i < nw; i++) { ra += sc[i*4]; rb += sc[i*4+1]; rc += sc[i*4+2]; rd += sc[i*4+3]; }
  __syncthreads();
  return make_float4(ra, rb, rc, rd);
}
__device__ inline float2 block_sum2(float a, float b, float* sc) {
#pragma unroll
  for (int o = 32; o >= 1; o >>= 1) { a += __shfl_down(a, o); b += __shfl_down(b, o); }
  const int lane = threadIdx.x & 63, w = threadIdx.x >> 6;
  const int nw = blockDim.x >> 6;
  if (lane == 0) { sc[w*2] = a; sc[w*2+1] = b; }
  __syncthreads();
  float ra = 0.f, rb = 0.f;
  for (int i = 0; i < nw; i++) { ra += sc[i*2]; rb += sc[i*2+1]; }
  __syncthreads();
  return make_float2(ra, rb);
}

// ---------------------------------------------------------------- fused LN(q),LN(k) + 16x16 attention
__global__ __launch_bounds__(256)
void attn_ln(const short* __restrict__ qp, const short* __restrict__ kv,
             const float* __restrict__ lnqw, const float* __restrict__ lnqb,
             const float* __restrict__ lnkw, const float* __restrict__ lnkb,
             short* __restrict__ att) {
  __shared__ float qs[HID];
  __shared__ float ks[NH * 65];
  __shared__ float vs[HID];
  __shared__ float aw[256];
  __shared__ float red[16];
  const int t = threadIdx.x;
  const size_t row = blockIdx.x;

  short4v q4 = *(const short4v*)(qp + row * HID + t * 4);
  short4v k4 = *(const short4v*)(kv + row * 2048 + t * 4);
  short4v v4 = *(const short4v*)(kv + row * 2048 + 1024 + t * 4);
  float qv[4], kvv[4];
  float sq = 0.f, sqq = 0.f, sk = 0.f, skk = 0.f;
#pragma unroll
  for (int i = 0; i < 4; i++) {
    qv[i] = bf2f(q4[i]); sq += qv[i]; sqq += qv[i] * qv[i];
    kvv[i] = bf2f(k4[i]); sk += kvv[i]; skk += kvv[i] * kvv[i];
  }
  float4 r4 = block_sum4(sq, sqq, sk, skk, red);
  float mq = r4.x / HID, vq = r4.y / HID - mq * mq;
  float rsq = rsqrtf(vq + 1e-5f);
  float mk = r4.z / HID, vv = r4.w / HID - mk * mk;
  float rsk = rsqrtf(vv + 1e-5f);
#pragma unroll
  for (int i = 0; i < 4; i++) {
    const int idx = t * 4 + i;
    qs[idx] = (qv[i] - mq) * rsq * lnqw[idx] + lnqb[idx];
    ks[(idx >> 6) * 65 + (idx & 63)] = (kvv[i] - mk) * rsk * lnkw[idx] + lnkb[idx];
    vs[idx] = bf2f(v4[i]);
  }
  __syncthreads();

  const int h = t >> 4, j = t & 15;
  float s = 0.f;
#pragma unroll 8
  for (int d = 0; d < 64; d++) s += qs[h * 64 + d] * ks[j * 65 + d];
  s *= 0.125f;
  float mx = s;
#pragma unroll
  for (int o = 8; o >= 1; o >>= 1) mx = fmaxf(mx, __shfl_xor(mx, o, 16));
  float e = __expf(s - mx);
  float sum = e;
#pragma unroll
  for (int o = 8; o >= 1; o >>= 1) sum += __shfl_xor(sum, o, 16);
  aw[t] = e / sum;
  __syncthreads();

  const int dB = (t & 15) * 4;
  float o0 = 0.f, o1 = 0.f, o2 = 0.f, o3 = 0.f;
#pragma unroll
  for (int jj = 0; jj < 16; jj++) {
    const float w = aw[h * 16 + jj];
    const float* vp = &vs[jj * 64 + dB];
    o0 += w * vp[0]; o1 += w * vp[1]; o2 += w * vp[2]; o3 += w * vp[3];
  }
  short4v o4;
  o4[0] = f2bf(o0); o4[1] = f2bf(o1); o4[2] = f2bf(o2); o4[3] = f2bf(o3);
  *(short4v*)(att + row * HID + h * 64 + dB) = o4;
}

// ---------------------------------------------------------------- final
__global__ __launch_bounds__(256)
void final_kernel(const short* __restrict__ opre, const short* __restrict__ cmb,
                  const float* __restrict__ egp, int rowsTot,
                  const float* __restrict__ bg2, const float* __restrict__ bc2,
                  const float* __restrict__ lnow, const float* __restrict__ lnob,
                  float* __restrict__ out) {
  __shared__ float red[8];
  const int t = threadIdx.x;
  const size_t row = blockIdx.x;
  short8 o8 = *(const short8*)(opre + row * QD + t * 8);
  short8 q8 = *(const short8*)(cmb + row * CMBD + t * 8);
  float x[8];
  float s = 0.f, ss = 0.f;
#pragma unroll
  for (int i = 0; i < 8; i++) { x[i] = bf2f(o8[i]); s += x[i]; ss += x[i] * x[i]; }
  float2 r = block_sum2(s, ss, red);
  float m = r.x / QD, v = r.y / QD - m * m;
  float rs = rsqrtf(v + 1e-5f);
  float gg = 1.f / (1.f + __expf(-(egp[row] + bg2[0])));
  float gc = 1.f / (1.f + __expf(-(egp[rowsTot + row] + bc2[0])));
  float g = gg * gc;
  float4v oa, ob;
#pragma unroll
  for (int i = 0; i < 8; i++) {
    const int c = t * 8 + i;
    float y = (x[i] - m) * rs * lnow[c] + lnob[c];
    float r2 = bf2f(q8[i]) + g * y;
    if (i < 4) oa[i] = r2; else ob[i - 4] = r2;
  }
  *(float4v*)(out + row * QD + t * 8) = oa;
  *(float4v*)(out + row * QD + t * 8 + 4) = ob;
}

// ---------------------------------------------------------------- launch
extern "C" void kernel_launch(void* const* d_in, const int* in_sizes, int n_in,
                              void* d_out, int out_size, void* d_ws, size_t ws_size,
                              hipStream_t stream) {
  const float* qf   = (const float*)d_in[0];
  const float* kf   = (const float*)d_in[1];
  const float* Wq   = (const float*)d_in[2];
  const float* bq   = (const float*)d_in[3];
  const float* lnqw = (const float*)d_in[4];
  const float* lnqb = (const float*)d_in[5];
  const float* Wk   = (const float*)d_in[6];
  const float* bk   = (const float*)d_in[7];
  const float* lnkw = (const float*)d_in[8];
  const float* lnkb = (const float*)d_in[9];
  const float* Wvk  = (const float*)d_in[12];
  const float* bvk  = (const float*)d_in[13];
  const float* Wo   = (const float*)d_in[14];
  const float* bo   = (const float*)d_in[15];
  const float* lnow = (const float*)d_in[16];
  const float* lnob = (const float*)d_in[17];
  const float* Wg1  = (const float*)d_in[18];
  const float* bg1  = (const float*)d_in[19];
  const float* Wg2  = (const float*)d_in[20];
  const float* bg2  = (const float*)d_in[21];
  const float* Wc1  = (const float*)d_in[22];
  const float* bc1  = (const float*)d_in[23];
  const float* Wc2  = (const float*)d_in[24];
  const float* bc2  = (const float*)d_in[25];

  const int rows = in_sizes[0] / QD;   // 16384

  char* ws = (char*)d_ws;
  size_t off = 0;
  auto alloc = [&](size_t bytes) -> char* {
    char* p = ws + off;
    off += (bytes + 255) & ~(size_t)255;
    return p;
  };
  short* cmb  = (short*)alloc((size_t)rows * CMBD * 2);
  short* wqb  = (short*)alloc((size_t)HID * QD * 2);
  short* wkv  = (short*)alloc((size_t)2 * HID * KD * 2);
  short* wob  = (short*)alloc((size_t)QD * HID * 2);
  unsigned char* wgc8 = (unsigned char*)alloc((size_t)2 * HID * CMBD);
  short* hgc  = (short*)alloc((size_t)rows * 2048 * 2);   // att; cmb8 aliases
  short* qp   = (short*)alloc((size_t)rows * HID * 2);
  short* kvp  = (short*)alloc((size_t)rows * 2048 * 2);
  float* egp  = (float*)alloc((size_t)2 * rows * 4);
  float* bgc  = (float*)alloc(2048 * 4);
  float* bkv  = (float*)alloc(2048 * 4);
  float* w2gc = (float*)alloc(2048 * 4);
  short* att  = hgc;
  unsigned char* cmb8 = (unsigned char*)hgc;  // gate reads before attn_ln writes att
  short* opre = kvp;

  const int egpN = 2 * rows;
  pack_params<<<(egpN + 6144) / 256, 256, 0, stream>>>(egp, egpN, bg1, bc1, bk, bvk,
                                                       Wg2, Wc2, bgc, bkv, w2gc);

  const int qblocks = (rows / 16) * (QD / 128);   // 16384
  const int kblocks = (rows / 16) * (KD / 128);   // 8192
  cvt_inputs<<<qblocks + kblocks, 256, 0, stream>>>(qf, kf, cmb, cmb8, qblocks);
  {
    WSeg s0{Wq,  wqb,                    2048};
    WSeg s1{Wk,  wkv,                    2048 + 1024};
    WSeg s2{Wvk, wkv + (size_t)HID * KD, 2048 + 2048};
    WSeg s3{Wo,  wob,                    2048 + 2048 + 2048};
    cvt_weights<<<s3.blkEnd, 256, 0, stream>>>(s0, s1, s2, s3);
  }
  cvt_w8<<<dim3(96, 8), 256, 0, stream>>>(Wg1, Wc1, wgc8);

  hipFuncSetAttribute((const void*)gemm256<EPI_NONE>,
                      hipFuncAttributeMaxDynamicSharedMemorySize, 131072);

  const dim3 blk(512);
  const int mt = rows / 256;   // 64
  const size_t lds = 131072;

  gemm_gate8<<<dim3(8, mt), blk, 0, stream>>>(cmb8, wgc8, bgc, w2gc, egp, rows);
  gemm256<EPI_NONE><<<dim3(1024 / 256, mt), blk, lds, stream>>>(cmb, CMBD, wqb, bq, qp, 1024, QD, nullptr, nullptr, 0);
  gemm256<EPI_NONE><<<dim3(2048 / 256, mt), blk, lds, stream>>>(cmb + QD, CMBD, wkv, bkv, kvp, 2048, KD, nullptr, nullptr, 0);
  attn_ln<<<rows, 256, 0, stream>>>(qp, kvp, lnqw, lnqb, lnkw, lnkb, att);
  gemm256<EPI_NONE><<<dim3(2048 / 256, mt), blk, lds, stream>>>(att, HID, wob, bo, opre, 2048, HID, nullptr, nullptr, 0);
  final_kernel<<<rows, 256, 0, stream>>>(opre, cmb, egp, rows, bg2, bc2, lnow, lnob, (float*)d_out);
}

// Round 23
// 578.317 us; speedup vs baseline: 1.0943x; 1.0009x over previous
//
#include <hip/hip_runtime.h>
#include <stdint.h>

#define QD 2048
#define KD 1024
#define HID 1024
#define NH 16
#define HD 64
#define CMBD 3072   // QD + KD

typedef float  f32x4   __attribute__((ext_vector_type(4)));
typedef short  short8  __attribute__((ext_vector_type(8)));
typedef short  short4v __attribute__((ext_vector_type(4)));
typedef float  float4v __attribute__((ext_vector_type(4)));

__device__ inline float bf2f(short s) {
  unsigned u = ((unsigned)(unsigned short)s) << 16;
  return __builtin_bit_cast(float, u);
}
__device__ inline short f2bf(float f) {
  unsigned u = __builtin_bit_cast(unsigned, f);
  u = u + 0x7fff + ((u >> 16) & 1);
  return (short)(u >> 16);
}
// e4m3fn (OCP), RNE, saturating
__device__ inline unsigned char f2f8(float f) {
  unsigned u = __builtin_bit_cast(unsigned, f);
  unsigned s = (u >> 24) & 0x80u;
  float a = fabsf(f);
  if (a >= 448.f) return (unsigned char)(s | 0x7E);
  if (a < 0.015625f) {
    int m = (int)(a * 512.f + 0.5f);
    if (m > 7) return (unsigned char)(s | 0x08);
    return (unsigned char)(s | m);
  }
  int ebits = (int)((u >> 23) & 0xFF) - 127;
  unsigned mant = u & 0x7FFFFF;
  unsigned keep = mant >> 20;
  unsigned rest = mant & 0xFFFFF;
  keep += (rest > 0x80000u) || (rest == 0x80000u && (keep & 1));
  if (keep == 8) { keep = 0; ebits += 1; }
  if (ebits > 8) return (unsigned char)(s | 0x7E);
  return (unsigned char)(s | ((unsigned)(ebits + 7) << 3) | keep);
}

// fp8 frag-blocked layout: addr(r,k) = (r>>8)*786432 + (k>>5)*8192 +
//   ((r>>4)&15)*512 + ((k>>3)&3)*128 + (r&15)*8 + (k&7)
__device__ inline size_t fp8addr(int r, int k) {
  return (size_t)(r >> 8) * 786432 + (size_t)(k >> 5) * 8192 +
         (size_t)((r >> 4) & 15) * 512 + (size_t)((k >> 3) & 3) * 128 +
         (size_t)(r & 15) * 8;
}

// ---------------------------------------------------------------- conversions
// Block = 16 rows x 128 cols; row = t>>4, col = (t&15)*8.
__global__ void cvt_inputs(const float* __restrict__ qf, const float* __restrict__ kf,
                           short* __restrict__ cmb, unsigned char* __restrict__ cmb8,
                           int qblocks) {
  const int b = blockIdx.x, t = threadIdx.x;
  int r, k;
  const float* src;
  if (b < qblocks) {
    const int rb = b >> 4, kb = b & 15;      // QD/128 = 16 col-blocks
    r = rb * 16 + (t >> 4); k = kb * 128 + (t & 15) * 8;
    src = qf + (size_t)r * QD + k;
  } else {
    const int b2 = b - qblocks;
    const int rb = b2 >> 3, kb = b2 & 7;     // KD/128 = 8 col-blocks
    r = rb * 16 + (t >> 4); k = kb * 128 + (t & 15) * 8;
    src = kf + (size_t)r * KD + k;
    k += QD;
  }
  float4v v0 = *(const float4v*)src;
  float4v v1 = *(const float4v*)(src + 4);
  short8 o;
  o[0] = f2bf(v0[0]); o[1] = f2bf(v0[1]); o[2] = f2bf(v0[2]); o[3] = f2bf(v0[3]);
  o[4] = f2bf(v1[0]); o[5] = f2bf(v1[1]); o[6] = f2bf(v1[2]); o[7] = f2bf(v1[3]);
  *(short8*)(cmb + (size_t)r * CMBD + k) = o;
  unsigned long long p =
      (unsigned long long)f2f8(v0[0])        | ((unsigned long long)f2f8(v0[1]) << 8)  |
      ((unsigned long long)f2f8(v0[2]) << 16)| ((unsigned long long)f2f8(v0[3]) << 24) |
      ((unsigned long long)f2f8(v1[0]) << 32)| ((unsigned long long)f2f8(v1[1]) << 40) |
      ((unsigned long long)f2f8(v1[2]) << 48)| ((unsigned long long)f2f8(v1[3]) << 56);
  *(unsigned long long*)(cmb8 + fp8addr(r, k)) = p;
}

struct WSeg { const float* s; short* d; int blkEnd; };
__global__ void cvt_weights(WSeg s0, WSeg s1, WSeg s2, WSeg s3) {
  int b = blockIdx.x;
  WSeg seg; int base;
  if      (b < s0.blkEnd) { seg = s0; base = 0; }
  else if (b < s1.blkEnd) { seg = s1; base = s0.blkEnd; }
  else if (b < s2.blkEnd) { seg = s2; base = s1.blkEnd; }
  else                    { seg = s3; base = s2.blkEnd; }
  const size_t i = ((size_t)(b - base) * 256 + threadIdx.x) * 4;
  float4v v = *(const float4v*)(seg.s + i);
  short4v o;
  o[0] = f2bf(v[0]); o[1] = f2bf(v[1]); o[2] = f2bf(v[2]); o[3] = f2bf(v[3]);
  *(short4v*)(seg.d + i) = o;
}

// Wg1||Wc1 -> fp8 frag-blocked wgc8; grid(96 kt, 8 band), 4 pieces/thread
__global__ void cvt_w8(const float* __restrict__ Wg1, const float* __restrict__ Wc1,
                       unsigned char* __restrict__ wgc8) {
  const int kt = blockIdx.x, band = blockIdx.y;
  unsigned char* dst = wgc8 + (size_t)band * 786432 + (size_t)kt * 8192;
  for (int p = threadIdx.x; p < 1024; p += 256) {
    const int grp = p >> 6, kq = (p >> 4) & 3, fr = p & 15;
    const int c = band * 256 + grp * 16 + fr;
    const int k = kt * 32 + kq * 8;
    const float* s = (c < 1024 ? Wg1 + (size_t)c * CMBD : Wc1 + (size_t)(c - 1024) * CMBD) + k;
    float4v v0 = *(const float4v*)s;
    float4v v1 = *(const float4v*)(s + 4);
    unsigned long long pk =
        (unsigned long long)f2f8(v0[0])        | ((unsigned long long)f2f8(v0[1]) << 8)  |
        ((unsigned long long)f2f8(v0[2]) << 16)| ((unsigned long long)f2f8(v0[3]) << 24) |
        ((unsigned long long)f2f8(v1[0]) << 32)| ((unsigned long long)f2f8(v1[1]) << 40) |
        ((unsigned long long)f2f8(v1[2]) << 48)| ((unsigned long long)f2f8(v1[3]) << 56);
    *(unsigned long long*)(dst + p * 8) = pk;
  }
}

// ---------------------------------------------------------------- pack
__global__ void pack_params(float* __restrict__ egp, int egpN,
                            const float* __restrict__ bg1, const float* __restrict__ bc1,
                            const float* __restrict__ bk,  const float* __restrict__ bvk,
                            const float* __restrict__ Wg2, const float* __restrict__ Wc2,
                            float* __restrict__ bgc, float* __restrict__ bkv,
                            float* __restrict__ w2gc) {
  int i = blockIdx.x * 256 + threadIdx.x;
  if (i < egpN) { egp[i] = 0.f; return; }
  i -= egpN;
  const int seg = i >> 10, idx = i & 1023;
  switch (seg) {
    case 0: bgc[idx]         = bg1[idx]; break;
    case 1: bgc[1024 + idx]  = bc1[idx]; break;
    case 2: bkv[idx]         = bk[idx];  break;
    case 3: bkv[1024 + idx]  = bvk[idx]; break;
    case 4: w2gc[idx]        = Wg2[idx]; break;
    case 5: w2gc[1024 + idx] = Wc2[idx]; break;
  }
}

// ---------------------------------------------------------------- common GEMM defs
#define EPI_NONE 0

typedef const __attribute__((address_space(1))) void gvoid_t;
typedef __attribute__((address_space(3))) void lvoid_t;

#define WAIT_VM(n)  asm volatile("s_waitcnt vmcnt(" #n ")" ::: "memory")

#define APAN(b, kp) (((b) * 2 + (kp)) * 8192)
#define BPAN(b, kp) (32768 + ((b) * 2 + (kp)) * 8192)

#define PHASE_MID                                        \
  __builtin_amdgcn_s_barrier();                          \
  asm volatile("s_waitcnt lgkmcnt(0)" ::: "memory");     \
  __builtin_amdgcn_s_setprio(1);

#define PHASE_END                                        \
  __builtin_amdgcn_s_setprio(0);                         \
  __builtin_amdgcn_s_barrier();

// ---------------------------------------------------------------- bf16 256x256 GEMM (verified) — Q/KV/O
template<int EPI>
__global__ __launch_bounds__(512, 2)
void gemm256(const short* __restrict__ A, size_t lda,
             const short* __restrict__ W,
             const float* __restrict__ bias,
             short* __restrict__ C, int N, int K,
             const float* __restrict__ w2, float* __restrict__ egp, int rowsTot) {
  extern __shared__ short ls[];
  const int tid  = threadIdx.x;
  const int lane = tid & 63;
  const int wave = tid >> 6;
  const int wm = wave >> 2, wn = wave & 3;
  const int fr = lane & 15, kq4 = lane >> 4;

  const int nwg = gridDim.x * gridDim.y;
  const int lin = blockIdx.y * gridDim.x + blockIdx.x;
  const int cpx = nwg >> 3;
  const int nid = (lin & 7) * cpx + (lin >> 3);
  const int bx = nid % gridDim.x, by = nid / gridDim.x;
  const size_t rowBase = (size_t)by * 256;
  const size_t colBase = (size_t)bx * 256;

  const int NTT = K >> 6;

  f32x4 acc[8][4];
#pragma unroll
  for (int mi = 0; mi < 8; mi++)
#pragma unroll
    for (int ni = 0; ni < 4; ni++) acc[mi][ni] = (f32x4){0.f, 0.f, 0.f, 0.f};

  const int frsw = (kq4 ^ ((fr >> 1) & 3)) * 8;

  const int grow  = tid >> 2;
  const int slotx = (tid & 3) ^ ((tid >> 3) & 3);
  const short* gAlo = A + (rowBase + grow) * lda + slotx * 8;
  const short* gAhi = gAlo + (size_t)128 * lda;
  const short* gBlo = W + (colBase + grow) * (size_t)K + slotx * 8;
  const short* gBhi = gBlo + (size_t)128 * K;
  short* const sdst = ls + tid * 8;

  auto STG_A = [&](int panOff, int kcol) {
    __builtin_amdgcn_global_load_lds((gvoid_t*)(gAlo + kcol), (lvoid_t*)(sdst + panOff),        16, 0, 0);
    __builtin_amdgcn_global_load_lds((gvoid_t*)(gAhi + kcol), (lvoid_t*)(sdst + panOff + 4096), 16, 0, 0);
  };
  auto STG_B = [&](int panOff, int kcol) {
    __builtin_amdgcn_global_load_lds((gvoid_t*)(gBlo + kcol), (lvoid_t*)(sdst + panOff),        16, 0, 0);
    __builtin_amdgcn_global_load_lds((gvoid_t*)(gBhi + kcol), (lvoid_t*)(sdst + panOff + 4096), 16, 0, 0);
  };

  STG_A(APAN(0, 0), 0);  STG_A(APAN(0, 1), 32);
  STG_B(BPAN(0, 0), 0);  STG_B(BPAN(0, 1), 32);
  STG_B(BPAN(1, 0), 64); STG_B(BPAN(1, 1), 96);
  WAIT_VM(4);
  __builtin_amdgcn_s_barrier();

  short8 fa0[8], fa1[8], fb0[4], fb1[4];

  for (int t = 0; t < NTT; t += 2) {
    const bool more = (t + 2 < NTT);
    const int kA1 = (t + 1) * 64;
    const int kE2 = (t + 2) * 64;
    const int kO3 = (t + 3) * 64;

#pragma unroll
    for (int m = 0; m < 4; m++) {
      const int r = (wm * 128 + m * 16 + fr) * 32 + frsw;
      fa0[m * 2 + 0] = *(const short8*)(ls + APAN(0, 0) + r);
      fa0[m * 2 + 1] = *(const short8*)(ls + APAN(0, 1) + r);
    }
#pragma unroll
    for (int n = 0; n < 2; n++) {
      const int r = (wn * 64 + n * 16 + fr) * 32 + frsw;
      fb0[n * 2 + 0] = *(const short8*)(ls + BPAN(0, 0) + r);
      fb0[n * 2 + 1] = *(const short8*)(ls + BPAN(0, 1) + r);
    }
    STG_A(APAN(1, 0), kA1);
    PHASE_MID
#pragma unroll
    for (int m = 0; m < 4; m++)
#pragma unroll
      for (int n = 0; n < 2; n++) {
        acc[m][n] = __builtin_amdgcn_mfma_f32_16x16x32_bf16(fa0[m*2+0], fb0[n*2+0], acc[m][n], 0, 0, 0);
        acc[m][n] = __builtin_amdgcn_mfma_f32_16x16x32_bf16(fa0[m*2+1], fb0[n*2+1], acc[m][n], 0, 0, 0);
      }
    PHASE_END

#pragma unroll
    for (int n = 0; n < 2; n++) {
      const int r = (wn * 64 + (n + 2) * 16 + fr) * 32 + frsw;
      fb1[n * 2 + 0] = *(const short8*)(ls + BPAN(0, 0) + r);
      fb1[n * 2 + 1] = *(const short8*)(ls + BPAN(0, 1) + r);
    }
    STG_A(APAN(1, 1), kA1 + 32);
    PHASE_MID
#pragma unroll
    for (int m = 0; m < 4; m++)
#pragma unroll
      for (int n = 0; n < 2; n++) {
        acc[m][n+2] = __builtin_amdgcn_mfma_f32_16x16x32_bf16(fa0[m*2+0], fb1[n*2+0], acc[m][n+2], 0, 0, 0);
        acc[m][n+2] = __builtin_amdgcn_mfma_f32_16x16x32_bf16(fa0[m*2+1], fb1[n*2+1], acc[m][n+2], 0, 0, 0);
      }
    PHASE_END

#pragma unroll
    for (int m = 0; m < 4; m++) {
      const int r = (wm * 128 + (m + 4) * 16 + fr) * 32 + frsw;
      fa1[m * 2 + 0] = *(const short8*)(ls + APAN(0, 0) + r);
      fa1[m * 2 + 1] = *(const short8*)(ls + APAN(0, 1) + r);
    }
    if (more) STG_B(BPAN(0, 0), kE2);
    PHASE_MID
#pragma unroll
    for (int m = 0; m < 4; m++)
#pragma unroll
      for (int n = 0; n < 2; n++) {
        acc[m+4][n] = __builtin_amdgcn_mfma_f32_16x16x32_bf16(fa1[m*2+0], fb0[n*2+0], acc[m+4][n], 0, 0, 0);
        acc[m+4][n] = __builtin_amdgcn_mfma_f32_16x16x32_bf16(fa1[m*2+1], fb0[n*2+1], acc[m+4][n], 0, 0, 0);
      }
    PHASE_END

    if (more) STG_B(BPAN(0, 1), kE2 + 32);
    PHASE_MID
#pragma unroll
    for (int m = 0; m < 4; m++)
#pragma unroll
      for (int n = 0; n < 2; n++) {
        acc[m+4][n+2] = __builtin_amdgcn_mfma_f32_16x16x32_bf16(fa1[m*2+0], fb1[n*2+0], acc[m+4][n+2], 0, 0, 0);
        acc[m+4][n+2] = __builtin_amdgcn_mfma_f32_16x16x32_bf16(fa1[m*2+1], fb1[n*2+1], acc[m+4][n+2], 0, 0, 0);
      }
    __builtin_amdgcn_s_setprio(0);
    if (more) { WAIT_VM(4); } else { WAIT_VM(0); }
    __builtin_amdgcn_s_barrier();

#pragma unroll
    for (int m = 0; m < 4; m++) {
      const int r = (wm * 128 + m * 16 + fr) * 32 + frsw;
      fa0[m * 2 + 0] = *(const short8*)(ls + APAN(1, 0) + r);
      fa0[m * 2 + 1] = *(const short8*)(ls + APAN(1, 1) + r);
    }
#pragma unroll
    for (int n = 0; n < 2; n++) {
      const int r = (wn * 64 + n * 16 + fr) * 32 + frsw;
      fb0[n * 2 + 0] = *(const short8*)(ls + BPAN(1, 0) + r);
      fb0[n * 2 + 1] = *(const short8*)(ls + BPAN(1, 1) + r);
    }
    if (more) STG_A(APAN(0, 0), kE2);
    PHASE_MID
#pragma unroll
    for (int m = 0; m < 4; m++)
#pragma unroll
      for (int n = 0; n < 2; n++) {
        acc[m][n] = __builtin_amdgcn_mfma_f32_16x16x32_bf16(fa0[m*2+0], fb0[n*2+0], acc[m][n], 0, 0, 0);
        acc[m][n] = __builtin_amdgcn_mfma_f32_16x16x32_bf16(fa0[m*2+1], fb0[n*2+1], acc[m][n], 0, 0, 0);
      }
    PHASE_END

#pragma unroll
    for (int n = 0; n < 2; n++) {
      const int r = (wn * 64 + (n + 2) * 16 + fr) * 32 + frsw;
      fb1[n * 2 + 0] = *(const short8*)(ls + BPAN(1, 0) + r);
      fb1[n * 2 + 1] = *(const short8*)(ls + BPAN(1, 1) + r);
    }
    if (more) STG_A(APAN(0, 1), kE2 + 32);
    PHASE_MID
#pragma unroll
    for (int m = 0; m < 4; m++)
#pragma unroll
      for (int n = 0; n < 2; n++) {
        acc[m][n+2] = __builtin_amdgcn_mfma_f32_16x16x32_bf16(fa0[m*2+0], fb1[n*2+0], acc[m][n+2], 0, 0, 0);
        acc[m][n+2] = __builtin_amdgcn_mfma_f32_16x16x32_bf16(fa0[m*2+1], fb1[n*2+1], acc[m][n+2], 0, 0, 0);
      }
    PHASE_END

#pragma unroll
    for (int m = 0; m < 4; m++) {
      const int r = (wm * 128 + (m + 4) * 16 + fr) * 32 + frsw;
      fa1[m * 2 + 0] = *(const short8*)(ls + APAN(1, 0) + r);
      fa1[m * 2 + 1] = *(const short8*)(ls + APAN(1, 1) + r);
    }
    if (more) STG_B(BPAN(1, 0), kO3);
    PHASE_MID
#pragma unroll
    for (int m = 0; m < 4; m++)
#pragma unroll
      for (int n = 0; n < 2; n++) {
        acc[m+4][n] = __builtin_amdgcn_mfma_f32_16x16x32_bf16(fa1[m*2+0], fb0[n*2+0], acc[m+4][n], 0, 0, 0);
        acc[m+4][n] = __builtin_amdgcn_mfma_f32_16x16x32_bf16(fa1[m*2+1], fb0[n*2+1], acc[m+4][n], 0, 0, 0);
      }
    PHASE_END

    if (more) STG_B(BPAN(1, 1), kO3 + 32);
    PHASE_MID
#pragma unroll
    for (int m = 0; m < 4; m++)
#pragma unroll
      for (int n = 0; n < 2; n++) {
        acc[m+4][n+2] = __builtin_amdgcn_mfma_f32_16x16x32_bf16(fa1[m*2+0], fb1[n*2+0], acc[m+4][n+2], 0, 0, 0);
        acc[m+4][n+2] = __builtin_amdgcn_mfma_f32_16x16x32_bf16(fa1[m*2+1], fb1[n*2+1], acc[m+4][n+2], 0, 0, 0);
      }
    __builtin_amdgcn_s_setprio(0);
    if (more) { WAIT_VM(4); }
    __builtin_amdgcn_s_barrier();
  }

#pragma unroll
  for (int mi = 0; mi < 8; mi++) {
    const size_t row0 = rowBase + wm * 128 + mi * 16 + kq4 * 4;
#pragma unroll
    for (int ni = 0; ni < 4; ni++) {
      const int col = (int)colBase + wn * 64 + ni * 16 + fr;
      const float bv = bias[col];
#pragma unroll
      for (int j = 0; j < 4; j++) {
        float x = acc[mi][ni][j] + bv;
        C[(row0 + j) * (size_t)N + col] = f2bf(x);
      }
    }
  }
}

// ---------------------------------------------------------------- fp8 gate GEMM, frag-blocked LDS (R20/R21 verified, 0 conflicts)
__global__ __launch_bounds__(512, 2)
void gemm_gate8(const unsigned char* __restrict__ A,
                const unsigned char* __restrict__ W,
                const float* __restrict__ bias,
                const float* __restrict__ w2, float* __restrict__ egp, int rowsTot) {
  __shared__ unsigned char ls[65536];
  const int tid  = threadIdx.x;
  const int lane = tid & 63;
  const int wave = tid >> 6;
  const int wm = wave >> 2, wn = wave & 3;
  const int fr = lane & 15, kq4 = lane >> 4;

  const int nwg = gridDim.x * gridDim.y;
  const int lin = blockIdx.y * gridDim.x + blockIdx.x;
  const int cpx = nwg >> 3;
  const int nid = (lin & 7) * cpx + (lin >> 3);
  const int bx = nid % gridDim.x, by = nid / gridDim.x;
  const size_t rowBase = (size_t)by * 256;
  const size_t colBase = (size_t)bx * 256;

  const int NTT = CMBD >> 6;               // 48

  f32x4 acc[8][4];
#pragma unroll
  for (int mi = 0; mi < 8; mi++)
#pragma unroll
    for (int ni = 0; ni < 4; ni++) acc[mi][ni] = (f32x4){0.f, 0.f, 0.f, 0.f};

  const int lp = kq4 * 128 + fr * 8;

  const unsigned char* gA = A + (size_t)by * 786432 + tid * 16;
  const unsigned char* gB = W + (size_t)bx * 786432 + tid * 16;
  unsigned char* const sdst = ls + tid * 16;

  auto STG_A = [&](int panOff, int kt) {
    __builtin_amdgcn_global_load_lds((gvoid_t*)(gA + (size_t)kt * 8192), (lvoid_t*)(sdst + panOff), 16, 0, 0);
  };
  auto STG_B = [&](int panOff, int kt) {
    __builtin_amdgcn_global_load_lds((gvoid_t*)(gB + (size_t)kt * 8192), (lvoid_t*)(sdst + 32768 + panOff), 16, 0, 0);
  };

  STG_A(APAN(0, 0), 0); STG_A(APAN(0, 1), 1);
  STG_B(APAN(0, 0), 0); STG_B(APAN(0, 1), 1);
  STG_B(APAN(1, 0), 2); STG_B(APAN(1, 1), 3);
  WAIT_VM(2);
  __builtin_amdgcn_s_barrier();

  long long fa0[8], fa1[8], fb0[4], fb1[4];

  for (int t = 0; t < NTT; t += 2) {
    const bool more = (t + 2 < NTT);
    const int k1 = 2 * (t + 1), k2 = 2 * (t + 2), k3 = 2 * (t + 3);

    // ===== even half: buf0 (tile t) =====
#pragma unroll
    for (int m = 0; m < 4; m++) {
      const int r = (wm * 8 + m) * 512 + lp;
      fa0[m * 2 + 0] = *(const long long*)(ls + APAN(0, 0) + r);
      fa0[m * 2 + 1] = *(const long long*)(ls + APAN(0, 1) + r);
    }
#pragma unroll
    for (int n = 0; n < 2; n++) {
      const int r = 32768 + (wn * 4 + n) * 512 + lp;
      fb0[n * 2 + 0] = *(const long long*)(ls + APAN(0, 0) + r);
      fb0[n * 2 + 1] = *(const long long*)(ls + APAN(0, 1) + r);
    }
    STG_A(APAN(1, 0), k1);
    PHASE_MID
#pragma unroll
    for (int m = 0; m < 4; m++)
#pragma unroll
      for (int n = 0; n < 2; n++) {
        acc[m][n] = __builtin_amdgcn_mfma_f32_16x16x32_fp8_fp8(fa0[m*2+0], fb0[n*2+0], acc[m][n], 0, 0, 0);
        acc[m][n] = __builtin_amdgcn_mfma_f32_16x16x32_fp8_fp8(fa0[m*2+1], fb0[n*2+1], acc[m][n], 0, 0, 0);
      }
    PHASE_END

#pragma unroll
    for (int n = 0; n < 2; n++) {
      const int r = 32768 + (wn * 4 + n + 2) * 512 + lp;
      fb1[n * 2 + 0] = *(const long long*)(ls + APAN(0, 0) + r);
      fb1[n * 2 + 1] = *(const long long*)(ls + APAN(0, 1) + r);
    }
    STG_A(APAN(1, 1), k1 + 1);
    PHASE_MID
#pragma unroll
    for (int m = 0; m < 4; m++)
#pragma unroll
      for (int n = 0; n < 2; n++) {
        acc[m][n+2] = __builtin_amdgcn_mfma_f32_16x16x32_fp8_fp8(fa0[m*2+0], fb1[n*2+0], acc[m][n+2], 0, 0, 0);
        acc[m][n+2] = __builtin_amdgcn_mfma_f32_16x16x32_fp8_fp8(fa0[m*2+1], fb1[n*2+1], acc[m][n+2], 0, 0, 0);
      }
    PHASE_END

#pragma unroll
    for (int m = 0; m < 4; m++) {
      const int r = (wm * 8 + m + 4) * 512 + lp;
      fa1[m * 2 + 0] = *(const long long*)(ls + APAN(0, 0) + r);
      fa1[m * 2 + 1] = *(const long long*)(ls + APAN(0, 1) + r);
    }
    if (more) STG_B(APAN(0, 0), k2);
    PHASE_MID
#pragma unroll
    for (int m = 0; m < 4; m++)
#pragma unroll
      for (int n = 0; n < 2; n++) {
        acc[m+4][n] = __builtin_amdgcn_mfma_f32_16x16x32_fp8_fp8(fa1[m*2+0], fb0[n*2+0], acc[m+4][n], 0, 0, 0);
        acc[m+4][n] = __builtin_amdgcn_mfma_f32_16x16x32_fp8_fp8(fa1[m*2+1], fb0[n*2+1], acc[m+4][n], 0, 0, 0);
      }
    PHASE_END

    if (more) STG_B(APAN(0, 1), k2 + 1);
    PHASE_MID
#pragma unroll
    for (int m = 0; m < 4; m++)
#pragma unroll
      for (int n = 0; n < 2; n++) {
        acc[m+4][n+2] = __builtin_amdgcn_mfma_f32_16x16x32_fp8_fp8(fa1[m*2+0], fb1[n*2+0], acc[m+4][n+2], 0, 0, 0);
        acc[m+4][n+2] = __builtin_amdgcn_mfma_f32_16x16x32_fp8_fp8(fa1[m*2+1], fb1[n*2+1], acc[m+4][n+2], 0, 0, 0);
      }
    __builtin_amdgcn_s_setprio(0);
    if (more) { WAIT_VM(2); } else { WAIT_VM(0); }
    __builtin_amdgcn_s_barrier();

    // ===== odd half: buf1 (tile t+1) =====
#pragma unroll
    for (int m = 0; m < 4; m++) {
      const int r = (wm * 8 + m) * 512 + lp;
      fa0[m * 2 + 0] = *(const long long*)(ls + APAN(1, 0) + r);
      fa0[m * 2 + 1] = *(const long long*)(ls + APAN(1, 1) + r);
    }
#pragma unroll
    for (int n = 0; n < 2; n++) {
      const int r = 32768 + (wn * 4 + n) * 512 + lp;
      fb0[n * 2 + 0] = *(const long long*)(ls + APAN(1, 0) + r);
      fb0[n * 2 + 1] = *(const long long*)(ls + APAN(1, 1) + r);
    }
    if (more) STG_A(APAN(0, 0), k2);
    PHASE_MID
#pragma unroll
    for (int m = 0; m < 4; m++)
#pragma unroll
      for (int n = 0; n < 2; n++) {
        acc[m][n] = __builtin_amdgcn_mfma_f32_16x16x32_fp8_fp8(fa0[m*2+0], fb0[n*2+0], acc[m][n], 0, 0, 0);
        acc[m][n] = __builtin_amdgcn_mfma_f32_16x16x32_fp8_fp8(fa0[m*2+1], fb0[n*2+1], acc[m][n], 0, 0, 0);
      }
    PHASE_END

#pragma unroll
    for (int n = 0; n < 2; n++) {
      const int r = 32768 + (wn * 4 + n + 2) * 512 + lp;
      fb1[n * 2 + 0] = *(const long long*)(ls + APAN(1, 0) + r);
      fb1[n * 2 + 1] = *(const long long*)(ls + APAN(1, 1) + r);
    }
    if (more) STG_A(APAN(0, 1), k2 + 1);
    PHASE_MID
#pragma unroll
    for (int m = 0; m < 4; m++)
#pragma unroll
      for (int n = 0; n < 2; n++) {
        acc[m][n+2] = __builtin_amdgcn_mfma_f32_16x16x32_fp8_fp8(fa0[m*2+0], fb1[n*2+0], acc[m][n+2], 0, 0, 0);
        acc[m][n+2] = __builtin_amdgcn_mfma_f32_16x16x32_fp8_fp8(fa0[m*2+1], fb1[n*2+1], acc[m][n+2], 0, 0, 0);
      }
    PHASE_END

#pragma unroll
    for (int m = 0; m < 4; m++) {
      const int r = (wm * 8 + m + 4) * 512 + lp;
      fa1[m * 2 + 0] = *(const long long*)(ls + APAN(1, 0) + r);
      fa1[m * 2 + 1] = *(const long long*)(ls + APAN(1, 1) + r);
    }
    if (more) STG_B(APAN(1, 0), k3);
    PHASE_MID
#pragma unroll
    for (int m = 0; m < 4; m++)
#pragma unroll
      for (int n = 0; n < 2; n++) {
        acc[m+4][n] = __builtin_amdgcn_mfma_f32_16x16x32_fp8_fp8(fa1[m*2+0], fb0[n*2+0], acc[m+4][n], 0, 0, 0);
        acc[m+4][n] = __builtin_amdgcn_mfma_f32_16x16x32_fp8_fp8(fa1[m*2+1], fb0[n*2+1], acc[m+4][n], 0, 0, 0);
      }
    PHASE_END

    if (more) STG_B(APAN(1, 1), k3 + 1);
    PHASE_MID
#pragma unroll
    for (int m = 0; m < 4; m++)
#pragma unroll
      for (int n = 0; n < 2; n++) {
        acc[m+4][n+2] = __builtin_amdgcn_mfma_f32_16x16x32_fp8_fp8(fa1[m*2+0], fb1[n*2+0], acc[m+4][n+2], 0, 0, 0);
        acc[m+4][n+2] = __builtin_amdgcn_mfma_f32_16x16x32_fp8_fp8(fa1[m*2+1], fb1[n*2+1], acc[m+4][n+2], 0, 0, 0);
      }
    __builtin_amdgcn_s_setprio(0);
    if (more) { WAIT_VM(2); }
    __builtin_amdgcn_s_barrier();
  }

  // fused gate epilogue
  float w2v[4], bvv[4];
#pragma unroll
  for (int ni = 0; ni < 4; ni++) {
    const int c = (int)colBase + wn * 64 + ni * 16 + fr;
    w2v[ni] = w2[c]; bvv[ni] = bias[c];
  }
  const int half = (colBase >= 1024) ? 1 : 0;
#pragma unroll
  for (int mi = 0; mi < 8; mi++) {
    float sj[4] = {0.f, 0.f, 0.f, 0.f};
#pragma unroll
    for (int ni = 0; ni < 4; ni++)
#pragma unroll
      for (int j = 0; j < 4; j++) {
        float x = acc[mi][ni][j] + bvv[ni];
        float g = 0.5f * x * (1.f + erff(x * 0.70710678118f));
        sj[j] += g * w2v[ni];
      }
#pragma unroll
    for (int j = 0; j < 4; j++) {
#pragma unroll
      for (int o = 8; o >= 1; o >>= 1) sj[j] += __shfl_xor(sj[j], o);
      if (fr == 0) {
        const int row = (int)rowBase + wm * 128 + mi * 16 + kq4 * 4 + j;
        atomicAdd(egp + half * rowsTot + row, sj[j]);
      }
    }
  }
}

// ---------------------------------------------------------------- block reduces
__device__ inline float4 block_sum4(float a, float b, float c, float d, float* sc) {
#pragma unroll
  for (int o = 32; o >= 1; o >>= 1) {
    a += __shfl_down(a, o); b += __shfl_down(b, o);
    c += __shfl_down(c, o); d += __shfl_down(d, o);
  }
  const int lane = threadIdx.x & 63, w = threadIdx.x >> 6;
  const int nw = blockDim.x >> 6;
  if (lane == 0) { sc[w*4] = a; sc[w*4+1] = b; sc[w*4+2] = c; sc[w*4+3] = d; }
  __syncthreads();
  float ra = 0.f, rb = 0.f, rc = 0.f, rd = 0.f;
  for (int i = 0; i < nw; i++) { ra += sc[i*4]; rb += sc[i*4+1]; rc += sc[i*4+2]; rd += sc[i*4+3]; }
  __syncthreads();
  return make_float4(ra, rb, rc, rd);
}
__device__ inline float2 block_sum2(float a, float b, float* sc) {
#pragma unroll
  for (int o = 32; o >= 1; o >>= 1) { a += __shfl_down(a, o); b += __shfl_down(b, o); }
  const int lane = threadIdx.x & 63, w = threadIdx.x >> 6;
  const int nw = blockDim.x >> 6;
  if (lane == 0) { sc[w*2] = a; sc[w*2+1] = b; }
  __syncthreads();
  float ra = 0.f, rb = 0.f;
  for (int i = 0; i < nw; i++) { ra += sc[i*2]; rb += sc[i*2+1]; }
  __syncthreads();
  return make_float2(ra, rb);
}

// ---------------------------------------------------------------- fused LN(q),LN(k) + 16x16 attention
__global__ __launch_bounds__(256)
void attn_ln(const short* __restrict__ qp, const short* __restrict__ kv,
             const float* __restrict__ lnqw, const float* __restrict__ lnqb,
             const float* __restrict__ lnkw, const float* __restrict__ lnkb,
             short* __restrict__ att) {
  __shared__ float qs[HID];
  __shared__ float ks[NH * 65];
  __shared__ float vs[HID];
  __shared__ float aw[256];
  __shared__ float red[16];
  const int t = threadIdx.x;
  const size_t row = blockIdx.x;

  short4v q4 = *(const short4v*)(qp + row * HID + t * 4);
  short4v k4 = *(const short4v*)(kv + row * 2048 + t * 4);
  short4v v4 = *(const short4v*)(kv + row * 2048 + 1024 + t * 4);
  float qv[4], kvv[4];
  float sq = 0.f, sqq = 0.f, sk = 0.f, skk = 0.f;
#pragma unroll
  for (int i = 0; i < 4; i++) {
    qv[i] = bf2f(q4[i]); sq += qv[i]; sqq += qv[i] * qv[i];
    kvv[i] = bf2f(k4[i]); sk += kvv[i]; skk += kvv[i] * kvv[i];
  }
  float4 r4 = block_sum4(sq, sqq, sk, skk, red);
  float mq = r4.x / HID, vq = r4.y / HID - mq * mq;
  float rsq = rsqrtf(vq + 1e-5f);
  float mk = r4.z / HID, vv = r4.w / HID - mk * mk;
  float rsk = rsqrtf(vv + 1e-5f);
#pragma unroll
  for (int i = 0; i < 4; i++) {
    const int idx = t * 4 + i;
    qs[idx] = (qv[i] - mq) * rsq * lnqw[idx] + lnqb[idx];
    ks[(idx >> 6) * 65 + (idx & 63)] = (kvv[i] - mk) * rsk * lnkw[idx] + lnkb[idx];
    vs[idx] = bf2f(v4[i]);
  }
  __syncthreads();

  const int h = t >> 4, j = t & 15;
  float s = 0.f;
#pragma unroll 8
  for (int d = 0; d < 64; d++) s += qs[h * 64 + d] * ks[j * 65 + d];
  s *= 0.125f;
  float mx = s;
#pragma unroll
  for (int o = 8; o >= 1; o >>= 1) mx = fmaxf(mx, __shfl_xor(mx, o, 16));
  float e = __expf(s - mx);
  float sum = e;
#pragma unroll
  for (int o = 8; o >= 1; o >>= 1) sum += __shfl_xor(sum, o, 16);
  aw[t] = e / sum;
  __syncthreads();

  const int dB = (t & 15) * 4;
  float o0 = 0.f, o1 = 0.f, o2 = 0.f, o3 = 0.f;
#pragma unroll
  for (int jj = 0; jj < 16; jj++) {
    const float w = aw[h * 16 + jj];
    const float* vp = &vs[jj * 64 + dB];
    o0 += w * vp[0]; o1 += w * vp[1]; o2 += w * vp[2]; o3 += w * vp[3];
  }
  short4v o4;
  o4[0] = f2bf(o0); o4[1] = f2bf(o1); o4[2] = f2bf(o2); o4[3] = f2bf(o3);
  *(short4v*)(att + row * HID + h * 64 + dB) = o4;
}

// ---------------------------------------------------------------- final
__global__ __launch_bounds__(256)
void final_kernel(const short* __restrict__ opre, const short* __restrict__ cmb,
                  const float* __restrict__ egp, int rowsTot,
                  const float* __restrict__ bg2, const float* __restrict__ bc2,
                  const float* __restrict__ lnow, const float* __restrict__ lnob,
                  float* __restrict__ out) {
  __shared__ float red[8];
  const int t = threadIdx.x;
  const size_t row = blockIdx.x;
  short8 o8 = *(const short8*)(opre + row * QD + t * 8);
  short8 q8 = *(const short8*)(cmb + row * CMBD + t * 8);
  float x[8];
  float s = 0.f, ss = 0.f;
#pragma unroll
  for (int i = 0; i < 8; i++) { x[i] = bf2f(o8[i]); s += x[i]; ss += x[i] * x[i]; }
  float2 r = block_sum2(s, ss, red);
  float m = r.x / QD, v = r.y / QD - m * m;
  float rs = rsqrtf(v + 1e-5f);
  float gg = 1.f / (1.f + __expf(-(egp[row] + bg2[0])));
  float gc = 1.f / (1.f + __expf(-(egp[rowsTot + row] + bc2[0])));
  float g = gg * gc;
  float4v oa, ob;
#pragma unroll
  for (int i = 0; i < 8; i++) {
    const int c = t * 8 + i;
    float y = (x[i] - m) * rs * lnow[c] + lnob[c];
    float r2 = bf2f(q8[i]) + g * y;
    if (i < 4) oa[i] = r2; else ob[i - 4] = r2;
  }
  *(float4v*)(out + row * QD + t * 8) = oa;
  *(float4v*)(out + row * QD + t * 8 + 4) = ob;
}

// ---------------------------------------------------------------- launch
extern "C" void kernel_launch(void* const* d_in, const int* in_sizes, int n_in,
                              void* d_out, int out_size, void* d_ws, size_t ws_size,
                              hipStream_t stream) {
  const float* qf   = (const float*)d_in[0];
  const float* kf   = (const float*)d_in[1];
  const float* Wq   = (const float*)d_in[2];
  const float* bq   = (const float*)d_in[3];
  const float* lnqw = (const float*)d_in[4];
  const float* lnqb = (const float*)d_in[5];
  const float* Wk   = (const float*)d_in[6];
  const float* bk   = (const float*)d_in[7];
  const float* lnkw = (const float*)d_in[8];
  const float* lnkb = (const float*)d_in[9];
  const float* Wvk  = (const float*)d_in[12];
  const float* bvk  = (const float*)d_in[13];
  const float* Wo   = (const float*)d_in[14];
  const float* bo   = (const float*)d_in[15];
  const float* lnow = (const float*)d_in[16];
  const float* lnob = (const float*)d_in[17];
  const float* Wg1  = (const float*)d_in[18];
  const float* bg1  = (const float*)d_in[19];
  const float* Wg2  = (const float*)d_in[20];
  const float* bg2  = (const float*)d_in[21];
  const float* Wc1  = (const float*)d_in[22];
  const float* bc1  = (const float*)d_in[23];
  const float* Wc2  = (const float*)d_in[24];
  const float* bc2  = (const float*)d_in[25];

  const int rows = in_sizes[0] / QD;   // 16384

  char* ws = (char*)d_ws;
  size_t off = 0;
  auto alloc = [&](size_t bytes) -> char* {
    char* p = ws + off;
    off += (bytes + 255) & ~(size_t)255;
    return p;
  };
  short* cmb  = (short*)alloc((size_t)rows * CMBD * 2);
  short* wqb  = (short*)alloc((size_t)HID * QD * 2);
  short* wkv  = (short*)alloc((size_t)2 * HID * KD * 2);
  short* wob  = (short*)alloc((size_t)QD * HID * 2);
  unsigned char* wgc8 = (unsigned char*)alloc((size_t)2 * HID * CMBD);
  short* hgc  = (short*)alloc((size_t)rows * 2048 * 2);   // att; cmb8 aliases
  short* qp   = (short*)alloc((size_t)rows * HID * 2);
  short* kvp  = (short*)alloc((size_t)rows * 2048 * 2);
  float* egp  = (float*)alloc((size_t)2 * rows * 4);
  float* bgc  = (float*)alloc(2048 * 4);
  float* bkv  = (float*)alloc(2048 * 4);
  float* w2gc = (float*)alloc(2048 * 4);
  short* att  = hgc;
  unsigned char* cmb8 = (unsigned char*)hgc;  // gate reads before attn_ln writes att
  short* opre = kvp;

  const int egpN = 2 * rows;
  pack_params<<<(egpN + 6144) / 256, 256, 0, stream>>>(egp, egpN, bg1, bc1, bk, bvk,
                                                       Wg2, Wc2, bgc, bkv, w2gc);

  const int qblocks = (rows / 16) * (QD / 128);   // 16384
  const int kblocks = (rows / 16) * (KD / 128);   // 8192
  cvt_inputs<<<qblocks + kblocks, 256, 0, stream>>>(qf, kf, cmb, cmb8, qblocks);
  {
    WSeg s0{Wq,  wqb,                    2048};
    WSeg s1{Wk,  wkv,                    2048 + 1024};
    WSeg s2{Wvk, wkv + (size_t)HID * KD, 2048 + 2048};
    WSeg s3{Wo,  wob,                    2048 + 2048 + 2048};
    cvt_weights<<<s3.blkEnd, 256, 0, stream>>>(s0, s1, s2, s3);
  }
  cvt_w8<<<dim3(96, 8), 256, 0, stream>>>(Wg1, Wc1, wgc8);

  hipFuncSetAttribute((const void*)gemm256<EPI_NONE>,
                      hipFuncAttributeMaxDynamicSharedMemorySize, 131072);

  const dim3 blk(512);
  const int mt = rows / 256;   // 64
  const size_t lds = 131072;

  gemm_gate8<<<dim3(8, mt), blk, 0, stream>>>(cmb8, wgc8, bgc, w2gc, egp, rows);
  gemm256<EPI_NONE><<<dim3(1024 / 256, mt), blk, lds, stream>>>(cmb, CMBD, wqb, bq, qp, 1024, QD, nullptr, nullptr, 0);
  gemm256<EPI_NONE><<<dim3(2048 / 256, mt), blk, lds, stream>>>(cmb + QD, CMBD, wkv, bkv, kvp, 2048, KD, nullptr, nullptr, 0);
  attn_ln<<<rows, 256, 0, stream>>>(qp, kvp, lnqw, lnqb, lnkw, lnkb, att);
  gemm256<EPI_NONE><<<dim3(2048 / 256, mt), blk, lds, stream>>>(att, HID, wob, bo, opre, 2048, HID, nullptr, nullptr, 0);
  final_kernel<<<rows, 256, 0, stream>>>(opre, cmb, egp, rows, bg2, bc2, lnow, lnob, (float*)d_out);
}